// Round 10
// baseline (105729.810 us; speedup 1.0000x reference)
//
#include <hip/hip_runtime.h>
#include <stdint.h>
#include <math.h>

#define S_ 256
#define B_ 1024
#define E_ 128
#define H_ 128
#define G4_ 512
#define NT 256

static const size_t OFF_P = 0;
static const size_t OFF_I = (size_t)S_ * B_ * S_;              // 67108864
static const size_t OFF_H = OFF_I + (size_t)S_ * B_;           // 67371008
static const size_t OFF_C = OFF_H + (size_t)B_ * H_;           // 67502080

template<typename T> struct alignas(2 * sizeof(T)) V2 { T x, y; };

// ---------------- threefry2x32 core (matches jax threefry2x32_p) ----------------
__device__ __forceinline__ void tf2x32(uint32_t k0, uint32_t k1,
                                       uint32_t x0, uint32_t x1,
                                       uint32_t& o0, uint32_t& o1) {
  uint32_t ks2 = k0 ^ k1 ^ 0x1BD11BDAu;
#define RO_(v,r) (((v) << (r)) | ((v) >> (32-(r))))
#define RND_(r) { x0 += x1; x1 = RO_(x1,r); x1 ^= x0; }
  x0 += k0; x1 += k1;
  RND_(13) RND_(15) RND_(26) RND_(6)
  x0 += k1; x1 += ks2 + 1u;
  RND_(17) RND_(29) RND_(16) RND_(24)
  x0 += ks2; x1 += k0 + 2u;
  RND_(13) RND_(15) RND_(26) RND_(6)
  x0 += k0; x1 += k1 + 3u;
  RND_(17) RND_(29) RND_(16) RND_(24)
  x0 += k1; x1 += ks2 + 4u;
  RND_(13) RND_(15) RND_(26) RND_(6)
  x0 += ks2; x1 += k0 + 5u;
  o0 = x0; o1 = x1;
#undef RND_
#undef RO_
}

// ---------------- fast branch-free f64 exp (rel err ~1e-16) ----------------
__device__ __forceinline__ double fexp(double x) {
  double t = x * 1.4426950408889634074;
  double n = rint(t);
  double r = __builtin_fma(n, -6.93147180369123816490e-01, x);   // ln2_hi (32b)
  r = __builtin_fma(n, -1.90821492927058770002e-10, r);          // ln2_lo
  double p = 2.08767569878681e-09;                                // 1/12!
  p = __builtin_fma(p, r, 2.50521083854417e-08);
  p = __builtin_fma(p, r, 2.75573192239859e-07);
  p = __builtin_fma(p, r, 2.75573192239859e-06);
  p = __builtin_fma(p, r, 2.48015873015873e-05);
  p = __builtin_fma(p, r, 1.98412698412698e-04);
  p = __builtin_fma(p, r, 1.38888888888889e-03);
  p = __builtin_fma(p, r, 8.33333333333333e-03);
  p = __builtin_fma(p, r, 4.16666666666667e-02);
  p = __builtin_fma(p, r, 1.66666666666667e-01);
  p = __builtin_fma(p, r, 5.0e-01);
  p = __builtin_fma(p, r, 1.0);
  p = __builtin_fma(p, r, 1.0);
  int ni = (int)n;
  double s = __longlong_as_double(((long long)(ni + 1023)) << 52);
  double res = p * s;
  return (x < -708.0) ? 0.0 : res;
}

__device__ __forceinline__ double ftanh(double x) {
  double a = fmin(fabs(x), 20.0);
  double w = fexp(-2.0 * a);
  double r = (1.0 - w) / (1.0 + w);
  return copysign(r, x);
}

__device__ __forceinline__ double fsigmoid(double x) {
  return 1.0 / (1.0 + fexp(-x));
}

__global__ void diag_write(float* out, float code) {
  if (threadIdx.x == 0 && blockIdx.x == 0) out[OFF_I] = code;
}

// ---------------- precompute tables (r8 scheme) ----------------
// e[b][g][s] = sum_h ctx[s][b][h]*W[h][g] + bias[g]  (f64)
// Eg[b][g][s] = exp(-2 e_g), Ep[b][g][s] = exp(-2 e_p), Elt[b][s][g] = e_g.
template<typename ETg, typename ETp, typename ETe>
__global__ __launch_bounds__(256) void precompute_e(
    const float* __restrict__ ctx,
    const float* __restrict__ gWr, const float* __restrict__ gbr,
    const float* __restrict__ pWr, const float* __restrict__ pbr,
    ETg* __restrict__ Eg, ETp* __restrict__ Ep, ETe* __restrict__ Elt) {
  __shared__ float cb[64][129];
  const int b = blockIdx.x;
  const int tid = threadIdx.x;
  const int sl = tid & 63;
  const int gq = tid >> 6;

  for (int s0 = 0; s0 < S_; s0 += 64) {
    __syncthreads();
    for (int i = tid; i < 64 * H_; i += 256) {
      int r = i >> 7, h = i & 127;
      cb[r][h] = ctx[((size_t)(s0 + r) * B_ + b) * H_ + h];
    }
    __syncthreads();
    const int s = s0 + sl;
    for (int g0 = 0; g0 < H_; g0 += 4) {
      int g = g0 + gq;
      double a = 0.0, a2 = 0.0;
#pragma unroll 8
      for (int h = 0; h < H_; ++h) {
        double c = (double)cb[sl][h];
        a  = fma(c, (double)gWr[h * H_ + g], a);
        a2 = fma(c, (double)pWr[h * H_ + g], a2);
      }
      double e1 = a + (double)gbr[g];
      double e2 = a2 + (double)pbr[g];
      size_t idx = ((size_t)b * H_ + g) * S_ + s;
      Eg[idx] = (ETg)fexp(-2.0 * e1);
      Ep[idx] = (ETp)fexp(-2.0 * e2);
      Elt[((size_t)b * S_ + s) * H_ + g] = (ETe)e1;
    }
  }
}

// ---------------- main persistent per-b decoder (f64 math, 256 thr) ----------------
// __launch_bounds__(256,4): 4 waves/SIMD floor -> <=128 VGPR, grid caps 4 blk/CU.
template<typename ETg, typename ETp, typename ETe>
__global__ __launch_bounds__(NT, 4) void decoder_main(
    const float* __restrict__ dec, const float* __restrict__ emb,
    const float* __restrict__ hx0, const float* __restrict__ cx0,
    const float* __restrict__ Wi, const float* __restrict__ bi,
    const float* __restrict__ Wh, const float* __restrict__ bh,
    const float* __restrict__ gWq, const float* __restrict__ gbq,
    const float* __restrict__ gv,
    const float* __restrict__ pWq, const float* __restrict__ pbq,
    const float* __restrict__ pv,
    const ETg* __restrict__ Eg_g, const ETp* __restrict__ Ep_g,
    const ETe* __restrict__ Elt_g,
    float* __restrict__ out) {
  __shared__ double gates[G4_];
  __shared__ double red0[NT];
  __shared__ double red1[NT];
  __shared__ double eq[H_], eq2[H_], glv[H_];
  __shared__ double sh[H_], sc[H_];
  __shared__ float  sx[E_];
  __shared__ double gl[S_];
  __shared__ double wbuf[S_];
  __shared__ double plv[S_];
  __shared__ double pex[S_];
  __shared__ float  gvs[H_], pvs[H_];
  __shared__ float  msk[S_];
  __shared__ uint32_t kk0[S_], kk1[S_];
  __shared__ double redM[4];
  __shared__ double redA[4];
  __shared__ int    redI[4];
  __shared__ int s_idx;

  const int b = blockIdx.x;
  const int tid = threadIdx.x;

  // ---- init ----
  if (tid < H_) {
    sh[tid] = (double)hx0[b * H_ + tid];
    sc[tid] = (double)cx0[b * H_ + tid];
    gvs[tid] = gv[tid]; pvs[tid] = pv[tid];
  } else {
    sx[tid - 128] = dec[b * E_ + (tid - 128)];
  }
  msk[tid] = 0.f;
  {
    // partitionable split: keys[t] = threefry2x32((0,42), (0,t))
    uint32_t a0, a1;
    tf2x32(0u, 42u, 0u, (uint32_t)tid, a0, a1);
    kk0[tid] = a0; kk1[tid] = a1;
  }
  const double bi_cA = (double)bi[tid];
  const double bi_cB = (double)bi[tid + 256];
  const double bh_cA = (double)bh[tid];
  const double bh_cB = (double)bh[tid + 256];
  const double gbq_c = (tid < H_) ? (double)gbq[tid] : 0.0;
  const double pbq_c = (tid < H_) ? (double)pbq[tid] : 0.0;
  const ETg* Eg_b  = Eg_g  + (size_t)b * H_ * S_;
  const ETp* Ep_b  = Ep_g  + (size_t)b * H_ * S_;
  const ETe* Elt_b = Elt_g + (size_t)b * S_ * H_;
  // D/H decomposition: tid = hf*128 + sc2; thread covers s-pair (2*sc2, 2*sc2+1),
  // h-range [hf*64, hf*64+64). Partials combined as (h<64)+(h>=64) — r5/r8 order.
  const int sc2 = tid & 127;
  const int hf  = tid >> 7;
  __syncthreads();

  for (int t = 0; t < S_; ++t) {
    // ---- A) gates = x@Wi + bi + h@Wh + bh (f64, seq-k, 2 gates/thread) ----
    {
      double a = 0.0, a2 = 0.0;
      const float* WiA = Wi + tid;
      const float* WiB = Wi + tid + 256;
#pragma unroll 8
      for (int k = 0; k < E_; ++k) {
        double xk = (double)sx[k];
        a  = fma(xk, (double)WiA[(size_t)k * G4_], a);
        a2 = fma(xk, (double)WiB[(size_t)k * G4_], a2);
      }
      a += bi_cA; a2 += bi_cB;
      const float* WhA = Wh + tid;
      const float* WhB = Wh + tid + 256;
#pragma unroll 8
      for (int k = 0; k < H_; ++k) {
        double hk = sh[k];
        a  = fma(hk, (double)WhA[(size_t)k * G4_], a);
        a2 = fma(hk, (double)WhB[(size_t)k * G4_], a2);
      }
      gates[tid] = a + bh_cA;
      gates[tid + 256] = a2 + bh_cB;
    }
    __syncthreads();
    // ---- B) LSTM elementwise ----
    if (tid < H_) {
      double si = fsigmoid(gates[tid]);
      double sf = fsigmoid(gates[H_ + tid]);
      double tg = ftanh(gates[2 * H_ + tid]);
      double so = fsigmoid(gates[3 * H_ + tid]);
      double cn = sf * sc[tid] + si * tg;
      double hn = so * ftanh(cn);
      sc[tid] = cn; sh[tid] = hn;
      if (t == S_ - 1) {
        out[OFF_H + (size_t)b * H_ + tid] = (float)hn;
        out[OFF_C + (size_t)b * H_ + tid] = (float)cn;
      }
    }
    __syncthreads();
    // ---- C) qp = hy@gWq + gbq; eq = exp(-2 qp) ----
    if (tid < H_) {
      double a = 0.0;
      const float* wq = gWq + tid;
#pragma unroll 8
      for (int k = 0; k < H_; ++k) a = fma(sh[k], (double)wq[k * H_], a);
      eq[tid] = fexp(-2.0 * (a + gbq_c));
    }
    __syncthreads();
    // ---- D) g logits: W = eq[h]*Eg; 8-deep load batch; fused div pair ----
    {
      const V2<ETg>* egp = reinterpret_cast<const V2<ETg>*>(Eg_b)
                           + (size_t)hf * 64 * (S_ / 2);
      double a0 = 0.0, a1 = 0.0;
      for (int hh0 = 0; hh0 < 64; hh0 += 8) {
        V2<ETg> vb[8];
#pragma unroll
        for (int j = 0; j < 8; ++j) vb[j] = egp[(hh0 + j) * (S_ / 2) + sc2];
#pragma unroll
        for (int j = 0; j < 8; ++j) {
          int h = hf * 64 + hh0 + j;
          double eqh = eq[h];
          double gvh = (double)gvs[h];
          double W0 = eqh * (double)vb[j].x;
          double W1 = eqh * (double)vb[j].y;
          double rd = 1.0 / ((1.0 + W0) * (1.0 + W1));
          double t0 = (1.0 - W0) * (1.0 + W1) * rd;
          double t1 = (1.0 - W1) * (1.0 + W0) * rd;
          a0 = fma(gvh, t0, a0);
          a1 = fma(gvh, t1, a1);
        }
      }
      red0[tid] = a0; red1[tid] = a1;
    }
    __syncthreads();
    if (tid < 128) {
      int s0 = 2 * tid, s1 = s0 + 1;
      double v0 = red0[tid] + red0[tid + 128];
      double v1 = red1[tid] + red1[tid + 128];
      gl[s0] = (msk[s0] != 0.f) ? -INFINITY : v0;
      gl[s1] = (msk[s1] != 0.f) ? -INFINITY : v1;
    }
    __syncthreads();
    // ---- E) softmax(gl) -> wbuf ----
    {
      double v = gl[tid];
      for (int o = 32; o; o >>= 1) v = fmax(v, __shfl_xor(v, o));
      if ((tid & 63) == 0) redM[tid >> 6] = v;
    }
    __syncthreads();
    {
      double m = fmax(fmax(redM[0], redM[1]), fmax(redM[2], redM[3]));
      pex[tid] = fexp(gl[tid] - m);
    }
    __syncthreads();
    {
      double sv = pex[tid];
      for (int o = 32; o; o >>= 1) sv += __shfl_xor(sv, o);
      if ((tid & 63) == 0) redM[tid >> 6] = sv;
    }
    __syncthreads();
    {
      double ssum = (redM[0] + redM[1]) + (redM[2] + redM[3]);
      wbuf[tid] = pex[tid] / ssum;
    }
    __syncthreads();
    // ---- F) g_l[g] = sum_s e_g[g][s]*w[s]; Elt[s][g] coalesced, 8-deep batch ----
    {
      int g = tid & 127, shalf = tid >> 7;
      const ETe* col = Elt_b + (size_t)shalf * 128 * H_ + g;
      const double* wp = wbuf + shalf * 128;
      double a = 0.0;
      for (int s0 = 0; s0 < 128; s0 += 8) {
        double vb[8];
#pragma unroll
        for (int j = 0; j < 8; ++j) vb[j] = (double)col[(size_t)(s0 + j) * H_];
#pragma unroll
        for (int j = 0; j < 8; ++j) a = fma(vb[j], wp[s0 + j], a);
      }
      red0[tid] = a;
    }
    __syncthreads();
    if (tid < H_) glv[tid] = red0[tid] + red0[tid + 128];
    __syncthreads();
    // ---- G) qp2 = g_l@pWq + pbq; eq2 = exp(-2 qp2) ----
    if (tid < H_) {
      double a = 0.0;
      const float* wq = pWq + tid;
#pragma unroll 8
      for (int k = 0; k < H_; ++k) a = fma(glv[k], (double)wq[k * H_], a);
      eq2[tid] = fexp(-2.0 * (a + pbq_c));
    }
    __syncthreads();
    // ---- H) p logits: same decomposition as D ----
    {
      const V2<ETp>* epp = reinterpret_cast<const V2<ETp>*>(Ep_b)
                           + (size_t)hf * 64 * (S_ / 2);
      double a0 = 0.0, a1 = 0.0;
      for (int hh0 = 0; hh0 < 64; hh0 += 8) {
        V2<ETp> vb[8];
#pragma unroll
        for (int j = 0; j < 8; ++j) vb[j] = epp[(hh0 + j) * (S_ / 2) + sc2];
#pragma unroll
        for (int j = 0; j < 8; ++j) {
          int h = hf * 64 + hh0 + j;
          double eqh = eq2[h];
          double pvh = (double)pvs[h];
          double W0 = eqh * (double)vb[j].x;
          double W1 = eqh * (double)vb[j].y;
          double rd = 1.0 / ((1.0 + W0) * (1.0 + W1));
          double t0 = (1.0 - W0) * (1.0 + W1) * rd;
          double t1 = (1.0 - W1) * (1.0 + W0) * rd;
          a0 = fma(pvh, t0, a0);
          a1 = fma(pvh, t1, a1);
        }
      }
      red0[tid] = a0; red1[tid] = a1;
    }
    __syncthreads();
    if (tid < 128) {
      int s0 = 2 * tid, s1 = s0 + 1;
      double u0 = red0[tid] + red0[tid + 128];
      double u1 = red1[tid] + red1[tid + 128];
      plv[s0] = (msk[s0] != 0.f) ? -INFINITY : (10.0 * ftanh(u0));
      plv[s1] = (msk[s1] != 0.f) ? -INFINITY : (10.0 * ftanh(u1));
    }
    __syncthreads();
    // ---- I) probs = softmax(plv) -> out (f32) ----
    {
      double v = plv[tid];
      for (int o = 32; o; o >>= 1) v = fmax(v, __shfl_xor(v, o));
      if ((tid & 63) == 0) redM[tid >> 6] = v;
    }
    __syncthreads();
    {
      double m2 = fmax(fmax(redM[0], redM[1]), fmax(redM[2], redM[3]));
      pex[tid] = fexp(plv[tid] - m2);
    }
    __syncthreads();
    {
      double sv = pex[tid];
      for (int o = 32; o; o >>= 1) sv += __shfl_xor(sv, o);
      if ((tid & 63) == 0) redM[tid >> 6] = sv;
    }
    __syncthreads();
    {
      double ssum2 = (redM[0] + redM[1]) + (redM[2] + redM[3]);
      out[OFF_P + ((size_t)t * B_ + b) * S_ + tid] = (float)(pex[tid] / ssum2);
    }
    // ---- J) gumbel + argmax (partitionable bits: o0^o1 of tf(key_t,(0,j))) ----
    double zval; int zidx;
    {
      uint32_t j = (uint32_t)(b * S_ + tid);
      uint32_t r0, r1;
      tf2x32(kk0[t], kk1[t], 0u, j, r0, r1);
      uint32_t bits = r0 ^ r1;
      float f = __uint_as_float((bits >> 9) | 0x3f800000u) - 1.0f;
      float u = fmaxf(f, 1.17549435082228751e-38f);
      double gmb = -log(-log((double)u));
      zval = gmb + plv[tid]; zidx = tid;
      for (int o = 32; o; o >>= 1) {
        double ov = __shfl_xor(zval, o);
        int    oi = __shfl_xor(zidx, o);
        if (ov > zval || (ov == zval && oi < zidx)) { zval = ov; zidx = oi; }
      }
      if ((tid & 63) == 0) { redA[tid >> 6] = zval; redI[tid >> 6] = zidx; }
    }
    __syncthreads();
    if (tid == 0) {
      double bv = redA[0]; int bx = redI[0];
#pragma unroll
      for (int w = 1; w < 4; ++w) {
        if (redA[w] > bv || (redA[w] == bv && redI[w] < bx)) { bv = redA[w]; bx = redI[w]; }
      }
      s_idx = bx;
      msk[bx] = 1.0f;
      out[OFF_I + (size_t)t * B_ + b] = (float)bx;
    }
    __syncthreads();
    // ---- K) gather next x ----
    if (tid < E_) sx[tid] = emb[((size_t)s_idx * B_ + b) * E_ + tid];
    __syncthreads();
  }
}

extern "C" void kernel_launch(void* const* d_in, const int* in_sizes, int n_in,
                              void* d_out, int out_size, void* d_ws, size_t ws_size,
                              hipStream_t stream) {
  const float* dec = (const float*)d_in[0];
  const float* emb = (const float*)d_in[1];
  const float* hx  = (const float*)d_in[2];
  const float* cx  = (const float*)d_in[3];
  const float* ctx = (const float*)d_in[4];
  const float* Wi  = (const float*)d_in[5];
  const float* bi  = (const float*)d_in[6];
  const float* Wh  = (const float*)d_in[7];
  const float* bh  = (const float*)d_in[8];
  const float* gWq = (const float*)d_in[9];
  const float* gbq = (const float*)d_in[10];
  const float* gWr = (const float*)d_in[11];
  const float* gbr = (const float*)d_in[12];
  const float* gv  = (const float*)d_in[13];
  const float* pWq = (const float*)d_in[14];
  const float* pbq = (const float*)d_in[15];
  const float* pWr = (const float*)d_in[16];
  const float* pbr = (const float*)d_in[17];
  const float* pv  = (const float*)d_in[18];
  float* out = (float*)d_out;
  char* w = (char*)d_ws;

  const size_t n_e = (size_t)B_ * H_ * S_;     // 33,554,432

  if (ws_size >= n_e * 24) {
    // tier A: Eg f64, Ep f64, Elt f64
    double* Eg = (double*)w;
    double* Ep = (double*)(w + n_e * 8);
    double* El = (double*)(w + n_e * 16);
    precompute_e<double,double,double><<<dim3(B_), dim3(256), 0, stream>>>(
        ctx, gWr, gbr, pWr, pbr, Eg, Ep, El);
    decoder_main<double,double,double><<<dim3(B_), dim3(NT), 0, stream>>>(
        dec, emb, hx, cx, Wi, bi, Wh, bh, gWq, gbq, gv, pWq, pbq, pv, Eg, Ep, El, out);
  } else if (ws_size >= n_e * 16) {
    // tier B: Eg f32, Ep f64, Elt f32
    float*  Eg = (float*)w;
    double* Ep = (double*)(w + n_e * 4);
    float*  El = (float*)(w + n_e * 12);
    precompute_e<float,double,float><<<dim3(B_), dim3(256), 0, stream>>>(
        ctx, gWr, gbr, pWr, pbr, Eg, Ep, El);
    decoder_main<float,double,float><<<dim3(B_), dim3(NT), 0, stream>>>(
        dec, emb, hx, cx, Wi, bi, Wh, bh, gWq, gbq, gv, pWq, pbq, pv, Eg, Ep, El, out);
  } else if (ws_size >= n_e * 12) {
    // tier C: all f32
    float* Eg = (float*)w;
    float* Ep = (float*)(w + n_e * 4);
    float* El = (float*)(w + n_e * 8);
    precompute_e<float,float,float><<<dim3(B_), dim3(256), 0, stream>>>(
        ctx, gWr, gbr, pWr, pbr, Eg, Ep, El);
    decoder_main<float,float,float><<<dim3(B_), dim3(NT), 0, stream>>>(
        dec, emb, hx, cx, Wi, bi, Wh, bh, gWq, gbq, gv, pWq, pbq, pv, Eg, Ep, El, out);
  } else {
    diag_write<<<dim3(1), dim3(64), 0, stream>>>(out, 700000.0f + (float)(ws_size >> 20));
  }
}

// Round 11
// 40004.236 us; speedup vs baseline: 2.6430x; 2.6430x over previous
//
#include <hip/hip_runtime.h>
#include <stdint.h>
#include <math.h>

#define S_ 256
#define B_ 1024
#define E_ 128
#define H_ 128
#define G4_ 512
#define NT 256

static const size_t OFF_P = 0;
static const size_t OFF_I = (size_t)S_ * B_ * S_;              // 67108864
static const size_t OFF_H = OFF_I + (size_t)S_ * B_;           // 67371008
static const size_t OFF_C = OFF_H + (size_t)B_ * H_;           // 67502080

template<typename T> struct alignas(2 * sizeof(T)) V2 { T x, y; };

// ---------------- threefry2x32 core (matches jax threefry2x32_p) ----------------
__device__ __forceinline__ void tf2x32(uint32_t k0, uint32_t k1,
                                       uint32_t x0, uint32_t x1,
                                       uint32_t& o0, uint32_t& o1) {
  uint32_t ks2 = k0 ^ k1 ^ 0x1BD11BDAu;
#define RO_(v,r) (((v) << (r)) | ((v) >> (32-(r))))
#define RND_(r) { x0 += x1; x1 = RO_(x1,r); x1 ^= x0; }
  x0 += k0; x1 += k1;
  RND_(13) RND_(15) RND_(26) RND_(6)
  x0 += k1; x1 += ks2 + 1u;
  RND_(17) RND_(29) RND_(16) RND_(24)
  x0 += ks2; x1 += k0 + 2u;
  RND_(13) RND_(15) RND_(26) RND_(6)
  x0 += k0; x1 += k1 + 3u;
  RND_(17) RND_(29) RND_(16) RND_(24)
  x0 += k1; x1 += ks2 + 4u;
  RND_(13) RND_(15) RND_(26) RND_(6)
  x0 += ks2; x1 += k0 + 5u;
  o0 = x0; o1 = x1;
#undef RND_
#undef RO_
}

// ---------------- fast branch-free f64 exp (rel err ~1e-16) ----------------
__device__ __forceinline__ double fexp(double x) {
  double t = x * 1.4426950408889634074;
  double n = rint(t);
  double r = __builtin_fma(n, -6.93147180369123816490e-01, x);   // ln2_hi (32b)
  r = __builtin_fma(n, -1.90821492927058770002e-10, r);          // ln2_lo
  double p = 2.08767569878681e-09;                                // 1/12!
  p = __builtin_fma(p, r, 2.50521083854417e-08);
  p = __builtin_fma(p, r, 2.75573192239859e-07);
  p = __builtin_fma(p, r, 2.75573192239859e-06);
  p = __builtin_fma(p, r, 2.48015873015873e-05);
  p = __builtin_fma(p, r, 1.98412698412698e-04);
  p = __builtin_fma(p, r, 1.38888888888889e-03);
  p = __builtin_fma(p, r, 8.33333333333333e-03);
  p = __builtin_fma(p, r, 4.16666666666667e-02);
  p = __builtin_fma(p, r, 1.66666666666667e-01);
  p = __builtin_fma(p, r, 5.0e-01);
  p = __builtin_fma(p, r, 1.0);
  p = __builtin_fma(p, r, 1.0);
  int ni = (int)n;
  double s = __longlong_as_double(((long long)(ni + 1023)) << 52);
  double res = p * s;
  return (x < -708.0) ? 0.0 : res;
}

__device__ __forceinline__ double ftanh(double x) {
  double a = fmin(fabs(x), 20.0);
  double w = fexp(-2.0 * a);
  double r = (1.0 - w) / (1.0 + w);
  return copysign(r, x);
}

__device__ __forceinline__ double fsigmoid(double x) {
  return 1.0 / (1.0 + fexp(-x));
}

__global__ void diag_write(float* out, float code) {
  if (threadIdx.x == 0 && blockIdx.x == 0) out[OFF_I] = code;
}

// ---------------- precompute tables (r8 scheme) ----------------
// e[b][g][s] = sum_h ctx[s][b][h]*W[h][g] + bias[g]  (f64)
// Eg[b][g][s] = exp(-2 e_g), Ep[b][g][s] = exp(-2 e_p), Elt[b][s][g] = e_g.
template<typename ETg, typename ETp, typename ETe>
__global__ __launch_bounds__(256) void precompute_e(
    const float* __restrict__ ctx,
    const float* __restrict__ gWr, const float* __restrict__ gbr,
    const float* __restrict__ pWr, const float* __restrict__ pbr,
    ETg* __restrict__ Eg, ETp* __restrict__ Ep, ETe* __restrict__ Elt) {
  __shared__ float cb[64][129];
  const int b = blockIdx.x;
  const int tid = threadIdx.x;
  const int sl = tid & 63;
  const int gq = tid >> 6;

  for (int s0 = 0; s0 < S_; s0 += 64) {
    __syncthreads();
    for (int i = tid; i < 64 * H_; i += 256) {
      int r = i >> 7, h = i & 127;
      cb[r][h] = ctx[((size_t)(s0 + r) * B_ + b) * H_ + h];
    }
    __syncthreads();
    const int s = s0 + sl;
    for (int g0 = 0; g0 < H_; g0 += 4) {
      int g = g0 + gq;
      double a = 0.0, a2 = 0.0;
#pragma unroll 8
      for (int h = 0; h < H_; ++h) {
        double c = (double)cb[sl][h];
        a  = fma(c, (double)gWr[h * H_ + g], a);
        a2 = fma(c, (double)pWr[h * H_ + g], a2);
      }
      double e1 = a + (double)gbr[g];
      double e2 = a2 + (double)pbr[g];
      size_t idx = ((size_t)b * H_ + g) * S_ + s;
      Eg[idx] = (ETg)fexp(-2.0 * e1);
      Ep[idx] = (ETp)fexp(-2.0 * e2);
      Elt[((size_t)b * S_ + s) * H_ + g] = (ETe)e1;
    }
  }
}

// ---------------- main persistent per-b decoder (f64 math, 256 thr) ----------------
// EXACT r8 structure (45.5 ms proven): no launch_bounds min-waves, no manual
// load batching — compiler scheduling of this loop shape is the measured optimum.
template<typename ETg, typename ETp, typename ETe>
__global__ __launch_bounds__(NT) void decoder_main(
    const float* __restrict__ dec, const float* __restrict__ emb,
    const float* __restrict__ hx0, const float* __restrict__ cx0,
    const float* __restrict__ Wi, const float* __restrict__ bi,
    const float* __restrict__ Wh, const float* __restrict__ bh,
    const float* __restrict__ gWq, const float* __restrict__ gbq,
    const float* __restrict__ gv,
    const float* __restrict__ pWq, const float* __restrict__ pbq,
    const float* __restrict__ pv,
    const ETg* __restrict__ Eg_g, const ETp* __restrict__ Ep_g,
    const ETe* __restrict__ Elt_g,
    float* __restrict__ out) {
  __shared__ double gates[G4_];
  __shared__ double red0[NT];
  __shared__ double red1[NT];
  __shared__ double eq[H_], eq2[H_], glv[H_];
  __shared__ double sh[H_], sc[H_];
  __shared__ float  sx[E_];
  __shared__ double gl[S_];
  __shared__ double wbuf[S_];
  __shared__ double plv[S_];
  __shared__ double pex[S_];
  __shared__ float  gvs[H_], pvs[H_];
  __shared__ float  msk[S_];
  __shared__ uint32_t kk0[S_], kk1[S_];
  __shared__ double redM[4];
  __shared__ double redA[4];
  __shared__ int    redI[4];
  __shared__ int s_idx;

  const int b = blockIdx.x;
  const int tid = threadIdx.x;

  // ---- init ----
  if (tid < H_) {
    sh[tid] = (double)hx0[b * H_ + tid];
    sc[tid] = (double)cx0[b * H_ + tid];
    gvs[tid] = gv[tid]; pvs[tid] = pv[tid];
  } else {
    sx[tid - 128] = dec[b * E_ + (tid - 128)];
  }
  msk[tid] = 0.f;
  {
    // partitionable split: keys[t] = threefry2x32((0,42), (0,t))
    uint32_t a0, a1;
    tf2x32(0u, 42u, 0u, (uint32_t)tid, a0, a1);
    kk0[tid] = a0; kk1[tid] = a1;
  }
  const double bi_cA = (double)bi[tid];
  const double bi_cB = (double)bi[tid + 256];
  const double bh_cA = (double)bh[tid];
  const double bh_cB = (double)bh[tid + 256];
  const double gbq_c = (tid < H_) ? (double)gbq[tid] : 0.0;
  const double pbq_c = (tid < H_) ? (double)pbq[tid] : 0.0;
  const ETg* Eg_b  = Eg_g  + (size_t)b * H_ * S_;
  const ETp* Ep_b  = Ep_g  + (size_t)b * H_ * S_;
  const ETe* Elt_b = Elt_g + (size_t)b * S_ * H_;
  // D/H decomposition: tid = hf*128 + sc2; thread covers s-pair (2*sc2, 2*sc2+1),
  // h-range [hf*64, hf*64+64). Partials combined as (h<64)+(h>=64) — r5/r8 order.
  const int sc2 = tid & 127;
  const int hf  = tid >> 7;
  __syncthreads();

  for (int t = 0; t < S_; ++t) {
    // ---- A) gates = x@Wi + bi + h@Wh + bh (f64, seq-k, 2 gates/thread) ----
    {
      double a = 0.0, a2 = 0.0;
      const float* WiA = Wi + tid;
      const float* WiB = Wi + tid + 256;
#pragma unroll 8
      for (int k = 0; k < E_; ++k) {
        double xk = (double)sx[k];
        a  = fma(xk, (double)WiA[(size_t)k * G4_], a);
        a2 = fma(xk, (double)WiB[(size_t)k * G4_], a2);
      }
      a += bi_cA; a2 += bi_cB;
      const float* WhA = Wh + tid;
      const float* WhB = Wh + tid + 256;
#pragma unroll 8
      for (int k = 0; k < H_; ++k) {
        double hk = sh[k];
        a  = fma(hk, (double)WhA[(size_t)k * G4_], a);
        a2 = fma(hk, (double)WhB[(size_t)k * G4_], a2);
      }
      gates[tid] = a + bh_cA;
      gates[tid + 256] = a2 + bh_cB;
    }
    __syncthreads();
    // ---- B) LSTM elementwise ----
    if (tid < H_) {
      double si = fsigmoid(gates[tid]);
      double sf = fsigmoid(gates[H_ + tid]);
      double tg = ftanh(gates[2 * H_ + tid]);
      double so = fsigmoid(gates[3 * H_ + tid]);
      double cn = sf * sc[tid] + si * tg;
      double hn = so * ftanh(cn);
      sc[tid] = cn; sh[tid] = hn;
      if (t == S_ - 1) {
        out[OFF_H + (size_t)b * H_ + tid] = (float)hn;
        out[OFF_C + (size_t)b * H_ + tid] = (float)cn;
      }
    }
    __syncthreads();
    // ---- C) qp = hy@gWq + gbq; eq = exp(-2 qp) ----
    if (tid < H_) {
      double a = 0.0;
      const float* wq = gWq + tid;
#pragma unroll 8
      for (int k = 0; k < H_; ++k) a = fma(sh[k], (double)wq[k * H_], a);
      eq[tid] = fexp(-2.0 * (a + gbq_c));
    }
    __syncthreads();
    // ---- D) g logits: W = eq[h]*Eg; h-half split, V2 loads (r8 loop shape) ----
    {
      const V2<ETg>* egp = reinterpret_cast<const V2<ETg>*>(Eg_b)
                           + (size_t)hf * 64 * (S_ / 2);
      double a0 = 0.0, a1 = 0.0;
#pragma unroll 8
      for (int hh = 0; hh < 64; ++hh) {
        int h = hf * 64 + hh;
        V2<ETg> w2 = egp[hh * (S_ / 2) + sc2];
        double eqh = eq[h];
        double gvh = (double)gvs[h];
        double W0 = eqh * (double)w2.x;
        double W1 = eqh * (double)w2.y;
        a0 = fma(gvh, (1.0 - W0) / (1.0 + W0), a0);
        a1 = fma(gvh, (1.0 - W1) / (1.0 + W1), a1);
      }
      red0[tid] = a0; red1[tid] = a1;
    }
    __syncthreads();
    if (tid < 128) {
      int s0 = 2 * tid, s1 = s0 + 1;
      double v0 = red0[tid] + red0[tid + 128];
      double v1 = red1[tid] + red1[tid + 128];
      gl[s0] = (msk[s0] != 0.f) ? -INFINITY : v0;
      gl[s1] = (msk[s1] != 0.f) ? -INFINITY : v1;
    }
    __syncthreads();
    // ---- E) softmax(gl) -> wbuf ----
    {
      double v = gl[tid];
      for (int o = 32; o; o >>= 1) v = fmax(v, __shfl_xor(v, o));
      if ((tid & 63) == 0) redM[tid >> 6] = v;
    }
    __syncthreads();
    {
      double m = fmax(fmax(redM[0], redM[1]), fmax(redM[2], redM[3]));
      pex[tid] = fexp(gl[tid] - m);
    }
    __syncthreads();
    {
      double sv = pex[tid];
      for (int o = 32; o; o >>= 1) sv += __shfl_xor(sv, o);
      if ((tid & 63) == 0) redM[tid >> 6] = sv;
    }
    __syncthreads();
    {
      double ssum = (redM[0] + redM[1]) + (redM[2] + redM[3]);
      wbuf[tid] = pex[tid] / ssum;
    }
    __syncthreads();
    // ---- F) g_l[g] = sum_s e_g[g][s]*w[s]  (Elt[s][g] coalesced, r8 shape) ----
    if (tid < H_) {
      double a = 0.0;
#pragma unroll 8
      for (int s = 0; s < S_; ++s)
        a = fma((double)Elt_b[(size_t)s * H_ + tid], wbuf[s], a);
      glv[tid] = a;
    }
    __syncthreads();
    // ---- G) qp2 = g_l@pWq + pbq; eq2 = exp(-2 qp2) ----
    if (tid < H_) {
      double a = 0.0;
      const float* wq = pWq + tid;
#pragma unroll 8
      for (int k = 0; k < H_; ++k) a = fma(glv[k], (double)wq[k * H_], a);
      eq2[tid] = fexp(-2.0 * (a + pbq_c));
    }
    __syncthreads();
    // ---- H) p logits: same decomposition as D ----
    {
      const V2<ETp>* epp = reinterpret_cast<const V2<ETp>*>(Ep_b)
                           + (size_t)hf * 64 * (S_ / 2);
      double a0 = 0.0, a1 = 0.0;
#pragma unroll 8
      for (int hh = 0; hh < 64; ++hh) {
        int h = hf * 64 + hh;
        V2<ETp> w2 = epp[hh * (S_ / 2) + sc2];
        double eqh = eq2[h];
        double pvh = (double)pvs[h];
        double W0 = eqh * (double)w2.x;
        double W1 = eqh * (double)w2.y;
        a0 = fma(pvh, (1.0 - W0) / (1.0 + W0), a0);
        a1 = fma(pvh, (1.0 - W1) / (1.0 + W1), a1);
      }
      red0[tid] = a0; red1[tid] = a1;
    }
    __syncthreads();
    if (tid < 128) {
      int s0 = 2 * tid, s1 = s0 + 1;
      double u0 = red0[tid] + red0[tid + 128];
      double u1 = red1[tid] + red1[tid + 128];
      plv[s0] = (msk[s0] != 0.f) ? -INFINITY : (10.0 * ftanh(u0));
      plv[s1] = (msk[s1] != 0.f) ? -INFINITY : (10.0 * ftanh(u1));
    }
    __syncthreads();
    // ---- I) probs = softmax(plv) -> out (f32) ----
    {
      double v = plv[tid];
      for (int o = 32; o; o >>= 1) v = fmax(v, __shfl_xor(v, o));
      if ((tid & 63) == 0) redM[tid >> 6] = v;
    }
    __syncthreads();
    {
      double m2 = fmax(fmax(redM[0], redM[1]), fmax(redM[2], redM[3]));
      pex[tid] = fexp(plv[tid] - m2);
    }
    __syncthreads();
    {
      double sv = pex[tid];
      for (int o = 32; o; o >>= 1) sv += __shfl_xor(sv, o);
      if ((tid & 63) == 0) redM[tid >> 6] = sv;
    }
    __syncthreads();
    {
      double ssum2 = (redM[0] + redM[1]) + (redM[2] + redM[3]);
      out[OFF_P + ((size_t)t * B_ + b) * S_ + tid] = (float)(pex[tid] / ssum2);
    }
    // ---- J) gumbel + argmax (partitionable bits: o0^o1 of tf(key_t,(0,j))) ----
    double zval; int zidx;
    {
      uint32_t j = (uint32_t)(b * S_ + tid);
      uint32_t r0, r1;
      tf2x32(kk0[t], kk1[t], 0u, j, r0, r1);
      uint32_t bits = r0 ^ r1;
      float f = __uint_as_float((bits >> 9) | 0x3f800000u) - 1.0f;
      float u = fmaxf(f, 1.17549435082228751e-38f);
      double gmb = -log(-log((double)u));
      zval = gmb + plv[tid]; zidx = tid;
      for (int o = 32; o; o >>= 1) {
        double ov = __shfl_xor(zval, o);
        int    oi = __shfl_xor(zidx, o);
        if (ov > zval || (ov == zval && oi < zidx)) { zval = ov; zidx = oi; }
      }
      if ((tid & 63) == 0) { redA[tid >> 6] = zval; redI[tid >> 6] = zidx; }
    }
    __syncthreads();
    if (tid == 0) {
      double bv = redA[0]; int bx = redI[0];
#pragma unroll
      for (int w = 1; w < 4; ++w) {
        if (redA[w] > bv || (redA[w] == bv && redI[w] < bx)) { bv = redA[w]; bx = redI[w]; }
      }
      s_idx = bx;
      msk[bx] = 1.0f;
      out[OFF_I + (size_t)t * B_ + b] = (float)bx;
    }
    __syncthreads();
    // ---- K) gather next x ----
    if (tid < E_) sx[tid] = emb[((size_t)s_idx * B_ + b) * E_ + tid];
    __syncthreads();
  }
}

extern "C" void kernel_launch(void* const* d_in, const int* in_sizes, int n_in,
                              void* d_out, int out_size, void* d_ws, size_t ws_size,
                              hipStream_t stream) {
  const float* dec = (const float*)d_in[0];
  const float* emb = (const float*)d_in[1];
  const float* hx  = (const float*)d_in[2];
  const float* cx  = (const float*)d_in[3];
  const float* ctx = (const float*)d_in[4];
  const float* Wi  = (const float*)d_in[5];
  const float* bi  = (const float*)d_in[6];
  const float* Wh  = (const float*)d_in[7];
  const float* bh  = (const float*)d_in[8];
  const float* gWq = (const float*)d_in[9];
  const float* gbq = (const float*)d_in[10];
  const float* gWr = (const float*)d_in[11];
  const float* gbr = (const float*)d_in[12];
  const float* gv  = (const float*)d_in[13];
  const float* pWq = (const float*)d_in[14];
  const float* pbq = (const float*)d_in[15];
  const float* pWr = (const float*)d_in[16];
  const float* pbr = (const float*)d_in[17];
  const float* pv  = (const float*)d_in[18];
  float* out = (float*)d_out;
  char* w = (char*)d_ws;

  const size_t n_e = (size_t)B_ * H_ * S_;     // 33,554,432

  if (ws_size >= n_e * 16) {
    // tier B': Eg f32 (g-softmax path, smoothed), Ep f64 (direct logit path),
    // Elt f32. 512 KB/block-step vs r8-A's 768 KB.
    float*  Eg = (float*)w;
    double* Ep = (double*)(w + n_e * 4);
    float*  El = (float*)(w + n_e * 12);
    precompute_e<float,double,float><<<dim3(B_), dim3(256), 0, stream>>>(
        ctx, gWr, gbr, pWr, pbr, Eg, Ep, El);
    decoder_main<float,double,float><<<dim3(B_), dim3(NT), 0, stream>>>(
        dec, emb, hx, cx, Wi, bi, Wh, bh, gWq, gbq, gv, pWq, pbq, pv, Eg, Ep, El, out);
  } else if (ws_size >= n_e * 12) {
    // tier C: all f32
    float* Eg = (float*)w;
    float* Ep = (float*)(w + n_e * 4);
    float* El = (float*)(w + n_e * 8);
    precompute_e<float,float,float><<<dim3(B_), dim3(256), 0, stream>>>(
        ctx, gWr, gbr, pWr, pbr, Eg, Ep, El);
    decoder_main<float,float,float><<<dim3(B_), dim3(NT), 0, stream>>>(
        dec, emb, hx, cx, Wi, bi, Wh, bh, gWq, gbq, gv, pWq, pbq, pv, Eg, Ep, El, out);
  } else {
    diag_write<<<dim3(1), dim3(64), 0, stream>>>(out, 700000.0f + (float)(ws_size >> 20));
  }
}

// Round 12
// 37197.910 us; speedup vs baseline: 2.8424x; 1.0754x over previous
//
#include <hip/hip_runtime.h>
#include <stdint.h>
#include <math.h>

#define S_ 256
#define B_ 1024
#define E_ 128
#define H_ 128
#define G4_ 512
#define NT 256

static const size_t OFF_P = 0;
static const size_t OFF_I = (size_t)S_ * B_ * S_;              // 67108864
static const size_t OFF_H = OFF_I + (size_t)S_ * B_;           // 67371008
static const size_t OFF_C = OFF_H + (size_t)B_ * H_;           // 67502080

template<typename T> struct alignas(2 * sizeof(T)) V2 { T x, y; };

// ---------------- threefry2x32 core (matches jax threefry2x32_p) ----------------
__device__ __forceinline__ void tf2x32(uint32_t k0, uint32_t k1,
                                       uint32_t x0, uint32_t x1,
                                       uint32_t& o0, uint32_t& o1) {
  uint32_t ks2 = k0 ^ k1 ^ 0x1BD11BDAu;
#define RO_(v,r) (((v) << (r)) | ((v) >> (32-(r))))
#define RND_(r) { x0 += x1; x1 = RO_(x1,r); x1 ^= x0; }
  x0 += k0; x1 += k1;
  RND_(13) RND_(15) RND_(26) RND_(6)
  x0 += k1; x1 += ks2 + 1u;
  RND_(17) RND_(29) RND_(16) RND_(24)
  x0 += ks2; x1 += k0 + 2u;
  RND_(13) RND_(15) RND_(26) RND_(6)
  x0 += k0; x1 += k1 + 3u;
  RND_(17) RND_(29) RND_(16) RND_(24)
  x0 += k1; x1 += ks2 + 4u;
  RND_(13) RND_(15) RND_(26) RND_(6)
  x0 += ks2; x1 += k0 + 5u;
  o0 = x0; o1 = x1;
#undef RND_
#undef RO_
}

// ---------------- fast branch-free f64 exp (rel err ~1e-16) ----------------
__device__ __forceinline__ double fexp(double x) {
  double t = x * 1.4426950408889634074;
  double n = rint(t);
  double r = __builtin_fma(n, -6.93147180369123816490e-01, x);   // ln2_hi (32b)
  r = __builtin_fma(n, -1.90821492927058770002e-10, r);          // ln2_lo
  double p = 2.08767569878681e-09;                                // 1/12!
  p = __builtin_fma(p, r, 2.50521083854417e-08);
  p = __builtin_fma(p, r, 2.75573192239859e-07);
  p = __builtin_fma(p, r, 2.75573192239859e-06);
  p = __builtin_fma(p, r, 2.48015873015873e-05);
  p = __builtin_fma(p, r, 1.98412698412698e-04);
  p = __builtin_fma(p, r, 1.38888888888889e-03);
  p = __builtin_fma(p, r, 8.33333333333333e-03);
  p = __builtin_fma(p, r, 4.16666666666667e-02);
  p = __builtin_fma(p, r, 1.66666666666667e-01);
  p = __builtin_fma(p, r, 5.0e-01);
  p = __builtin_fma(p, r, 1.0);
  p = __builtin_fma(p, r, 1.0);
  int ni = (int)n;
  double s = __longlong_as_double(((long long)(ni + 1023)) << 52);
  double res = p * s;
  return (x < -708.0) ? 0.0 : res;
}

__device__ __forceinline__ double ftanh(double x) {
  double a = fmin(fabs(x), 20.0);
  double w = fexp(-2.0 * a);
  double r = (1.0 - w) / (1.0 + w);
  return copysign(r, x);
}

__device__ __forceinline__ double fsigmoid(double x) {
  return 1.0 / (1.0 + fexp(-x));
}

__global__ void diag_write(float* out, float code) {
  if (threadIdx.x == 0 && blockIdx.x == 0) out[OFF_I] = code;
}

// ---------------- precompute tables (r8 scheme) ----------------
// e[b][g][s] = sum_h ctx[s][b][h]*W[h][g] + bias[g]  (f64)
// Eg[b][g][s] = exp(-2 e_g), Ep[b][g][s] = exp(-2 e_p), Elt[b][s][g] = e_g.
template<typename ETg, typename ETp, typename ETe>
__global__ __launch_bounds__(256) void precompute_e(
    const float* __restrict__ ctx,
    const float* __restrict__ gWr, const float* __restrict__ gbr,
    const float* __restrict__ pWr, const float* __restrict__ pbr,
    ETg* __restrict__ Eg, ETp* __restrict__ Ep, ETe* __restrict__ Elt) {
  __shared__ float cb[64][129];
  const int b = blockIdx.x;
  const int tid = threadIdx.x;
  const int sl = tid & 63;
  const int gq = tid >> 6;

  for (int s0 = 0; s0 < S_; s0 += 64) {
    __syncthreads();
    for (int i = tid; i < 64 * H_; i += 256) {
      int r = i >> 7, h = i & 127;
      cb[r][h] = ctx[((size_t)(s0 + r) * B_ + b) * H_ + h];
    }
    __syncthreads();
    const int s = s0 + sl;
    for (int g0 = 0; g0 < H_; g0 += 4) {
      int g = g0 + gq;
      double a = 0.0, a2 = 0.0;
#pragma unroll 8
      for (int h = 0; h < H_; ++h) {
        double c = (double)cb[sl][h];
        a  = fma(c, (double)gWr[h * H_ + g], a);
        a2 = fma(c, (double)pWr[h * H_ + g], a2);
      }
      double e1 = a + (double)gbr[g];
      double e2 = a2 + (double)pbr[g];
      size_t idx = ((size_t)b * H_ + g) * S_ + s;
      Eg[idx] = (ETg)fexp(-2.0 * e1);
      Ep[idx] = (ETp)fexp(-2.0 * e2);
      Elt[((size_t)b * S_ + s) * H_ + g] = (ETe)e1;
    }
  }
}

// ---------------- main persistent per-b decoder (f64 math, 256 thr) ----------------
// EXACT r8/r11 structure (proven): no launch_bounds min-waves, no manual
// load batching — compiler scheduling of this loop shape is the measured optimum.
template<typename ETg, typename ETp, typename ETe>
__global__ __launch_bounds__(NT) void decoder_main(
    const float* __restrict__ dec, const float* __restrict__ emb,
    const float* __restrict__ hx0, const float* __restrict__ cx0,
    const float* __restrict__ Wi, const float* __restrict__ bi,
    const float* __restrict__ Wh, const float* __restrict__ bh,
    const float* __restrict__ gWq, const float* __restrict__ gbq,
    const float* __restrict__ gv,
    const float* __restrict__ pWq, const float* __restrict__ pbq,
    const float* __restrict__ pv,
    const ETg* __restrict__ Eg_g, const ETp* __restrict__ Ep_g,
    const ETe* __restrict__ Elt_g,
    float* __restrict__ out) {
  __shared__ double gates[G4_];
  __shared__ double red0[NT];
  __shared__ double red1[NT];
  __shared__ double eq[H_], eq2[H_], glv[H_];
  __shared__ double sh[H_], sc[H_];
  __shared__ float  sx[E_];
  __shared__ double gl[S_];
  __shared__ double wbuf[S_];
  __shared__ double plv[S_];
  __shared__ double pex[S_];
  __shared__ float  gvs[H_], pvs[H_];
  __shared__ float  msk[S_];
  __shared__ uint32_t kk0[S_], kk1[S_];
  __shared__ double redM[4];
  __shared__ double redA[4];
  __shared__ int    redI[4];
  __shared__ int s_idx;

  const int b = blockIdx.x;
  const int tid = threadIdx.x;

  // ---- init ----
  if (tid < H_) {
    sh[tid] = (double)hx0[b * H_ + tid];
    sc[tid] = (double)cx0[b * H_ + tid];
    gvs[tid] = gv[tid]; pvs[tid] = pv[tid];
  } else {
    sx[tid - 128] = dec[b * E_ + (tid - 128)];
  }
  msk[tid] = 0.f;
  {
    // partitionable split: keys[t] = threefry2x32((0,42), (0,t))
    uint32_t a0, a1;
    tf2x32(0u, 42u, 0u, (uint32_t)tid, a0, a1);
    kk0[tid] = a0; kk1[tid] = a1;
  }
  const double bi_cA = (double)bi[tid];
  const double bi_cB = (double)bi[tid + 256];
  const double bh_cA = (double)bh[tid];
  const double bh_cB = (double)bh[tid + 256];
  const double gbq_c = (tid < H_) ? (double)gbq[tid] : 0.0;
  const double pbq_c = (tid < H_) ? (double)pbq[tid] : 0.0;
  const ETg* Eg_b  = Eg_g  + (size_t)b * H_ * S_;
  const ETp* Ep_b  = Ep_g  + (size_t)b * H_ * S_;
  const ETe* Elt_b = Elt_g + (size_t)b * S_ * H_;
  // D/H decomposition: tid = hf*128 + sc2; thread covers s-pair (2*sc2, 2*sc2+1),
  // h-range [hf*64, hf*64+64). Partials combined as (h<64)+(h>=64) — r5/r8 order.
  const int sc2 = tid & 127;
  const int hf  = tid >> 7;
  __syncthreads();

  for (int t = 0; t < S_; ++t) {
    // ---- A) gates = x@Wi + bi + h@Wh + bh (f64, seq-k, 2 gates/thread) ----
    {
      double a = 0.0, a2 = 0.0;
      const float* WiA = Wi + tid;
      const float* WiB = Wi + tid + 256;
#pragma unroll 8
      for (int k = 0; k < E_; ++k) {
        double xk = (double)sx[k];
        a  = fma(xk, (double)WiA[(size_t)k * G4_], a);
        a2 = fma(xk, (double)WiB[(size_t)k * G4_], a2);
      }
      a += bi_cA; a2 += bi_cB;
      const float* WhA = Wh + tid;
      const float* WhB = Wh + tid + 256;
#pragma unroll 8
      for (int k = 0; k < H_; ++k) {
        double hk = sh[k];
        a  = fma(hk, (double)WhA[(size_t)k * G4_], a);
        a2 = fma(hk, (double)WhB[(size_t)k * G4_], a2);
      }
      gates[tid] = a + bh_cA;
      gates[tid + 256] = a2 + bh_cB;
    }
    __syncthreads();
    // ---- B) LSTM elementwise ----
    if (tid < H_) {
      double si = fsigmoid(gates[tid]);
      double sf = fsigmoid(gates[H_ + tid]);
      double tg = ftanh(gates[2 * H_ + tid]);
      double so = fsigmoid(gates[3 * H_ + tid]);
      double cn = sf * sc[tid] + si * tg;
      double hn = so * ftanh(cn);
      sc[tid] = cn; sh[tid] = hn;
      if (t == S_ - 1) {
        out[OFF_H + (size_t)b * H_ + tid] = (float)hn;
        out[OFF_C + (size_t)b * H_ + tid] = (float)cn;
      }
    }
    __syncthreads();
    // ---- C) qp = hy@gWq + gbq; eq = exp(-2 qp) ----
    if (tid < H_) {
      double a = 0.0;
      const float* wq = gWq + tid;
#pragma unroll 8
      for (int k = 0; k < H_; ++k) a = fma(sh[k], (double)wq[k * H_], a);
      eq[tid] = fexp(-2.0 * (a + gbq_c));
    }
    __syncthreads();
    // ---- D) g logits: W = eq[h]*Eg; h-half split, V2 loads (r8 loop shape) ----
    {
      const V2<ETg>* egp = reinterpret_cast<const V2<ETg>*>(Eg_b)
                           + (size_t)hf * 64 * (S_ / 2);
      double a0 = 0.0, a1 = 0.0;
#pragma unroll 8
      for (int hh = 0; hh < 64; ++hh) {
        int h = hf * 64 + hh;
        V2<ETg> w2 = egp[hh * (S_ / 2) + sc2];
        double eqh = eq[h];
        double gvh = (double)gvs[h];
        double W0 = eqh * (double)w2.x;
        double W1 = eqh * (double)w2.y;
        a0 = fma(gvh, (1.0 - W0) / (1.0 + W0), a0);
        a1 = fma(gvh, (1.0 - W1) / (1.0 + W1), a1);
      }
      red0[tid] = a0; red1[tid] = a1;
    }
    __syncthreads();
    if (tid < 128) {
      int s0 = 2 * tid, s1 = s0 + 1;
      double v0 = red0[tid] + red0[tid + 128];
      double v1 = red1[tid] + red1[tid + 128];
      gl[s0] = (msk[s0] != 0.f) ? -INFINITY : v0;
      gl[s1] = (msk[s1] != 0.f) ? -INFINITY : v1;
    }
    __syncthreads();
    // ---- E) softmax(gl) -> wbuf ----
    {
      double v = gl[tid];
      for (int o = 32; o; o >>= 1) v = fmax(v, __shfl_xor(v, o));
      if ((tid & 63) == 0) redM[tid >> 6] = v;
    }
    __syncthreads();
    {
      double m = fmax(fmax(redM[0], redM[1]), fmax(redM[2], redM[3]));
      pex[tid] = fexp(gl[tid] - m);
    }
    __syncthreads();
    {
      double sv = pex[tid];
      for (int o = 32; o; o >>= 1) sv += __shfl_xor(sv, o);
      if ((tid & 63) == 0) redM[tid >> 6] = sv;
    }
    __syncthreads();
    {
      double ssum = (redM[0] + redM[1]) + (redM[2] + redM[3]);
      wbuf[tid] = pex[tid] / ssum;
    }
    __syncthreads();
    // ---- F) g_l[g] = sum_s e_g[g][s]*w[s]  (Elt[s][g] coalesced, r8 shape) ----
    if (tid < H_) {
      double a = 0.0;
#pragma unroll 8
      for (int s = 0; s < S_; ++s)
        a = fma((double)Elt_b[(size_t)s * H_ + tid], wbuf[s], a);
      glv[tid] = a;
    }
    __syncthreads();
    // ---- G) qp2 = g_l@pWq + pbq; eq2 = exp(-2 qp2) ----
    if (tid < H_) {
      double a = 0.0;
      const float* wq = pWq + tid;
#pragma unroll 8
      for (int k = 0; k < H_; ++k) a = fma(glv[k], (double)wq[k * H_], a);
      eq2[tid] = fexp(-2.0 * (a + pbq_c));
    }
    __syncthreads();
    // ---- H) p logits: same decomposition as D ----
    {
      const V2<ETp>* epp = reinterpret_cast<const V2<ETp>*>(Ep_b)
                           + (size_t)hf * 64 * (S_ / 2);
      double a0 = 0.0, a1 = 0.0;
#pragma unroll 8
      for (int hh = 0; hh < 64; ++hh) {
        int h = hf * 64 + hh;
        V2<ETp> w2 = epp[hh * (S_ / 2) + sc2];
        double eqh = eq2[h];
        double pvh = (double)pvs[h];
        double W0 = eqh * (double)w2.x;
        double W1 = eqh * (double)w2.y;
        a0 = fma(pvh, (1.0 - W0) / (1.0 + W0), a0);
        a1 = fma(pvh, (1.0 - W1) / (1.0 + W1), a1);
      }
      red0[tid] = a0; red1[tid] = a1;
    }
    __syncthreads();
    if (tid < 128) {
      int s0 = 2 * tid, s1 = s0 + 1;
      double u0 = red0[tid] + red0[tid + 128];
      double u1 = red1[tid] + red1[tid + 128];
      plv[s0] = (msk[s0] != 0.f) ? -INFINITY : (10.0 * ftanh(u0));
      plv[s1] = (msk[s1] != 0.f) ? -INFINITY : (10.0 * ftanh(u1));
    }
    __syncthreads();
    // ---- I) probs = softmax(plv) -> out (f32) ----
    {
      double v = plv[tid];
      for (int o = 32; o; o >>= 1) v = fmax(v, __shfl_xor(v, o));
      if ((tid & 63) == 0) redM[tid >> 6] = v;
    }
    __syncthreads();
    {
      double m2 = fmax(fmax(redM[0], redM[1]), fmax(redM[2], redM[3]));
      pex[tid] = fexp(plv[tid] - m2);
    }
    __syncthreads();
    {
      double sv = pex[tid];
      for (int o = 32; o; o >>= 1) sv += __shfl_xor(sv, o);
      if ((tid & 63) == 0) redM[tid >> 6] = sv;
    }
    __syncthreads();
    {
      double ssum2 = (redM[0] + redM[1]) + (redM[2] + redM[3]);
      out[OFF_P + ((size_t)t * B_ + b) * S_ + tid] = (float)(pex[tid] / ssum2);
    }
    // ---- J) gumbel + argmax (partitionable bits: o0^o1 of tf(key_t,(0,j))) ----
    double zval; int zidx;
    {
      uint32_t j = (uint32_t)(b * S_ + tid);
      uint32_t r0, r1;
      tf2x32(kk0[t], kk1[t], 0u, j, r0, r1);
      uint32_t bits = r0 ^ r1;
      float f = __uint_as_float((bits >> 9) | 0x3f800000u) - 1.0f;
      float u = fmaxf(f, 1.17549435082228751e-38f);
      double gmb = -log(-log((double)u));
      zval = gmb + plv[tid]; zidx = tid;
      for (int o = 32; o; o >>= 1) {
        double ov = __shfl_xor(zval, o);
        int    oi = __shfl_xor(zidx, o);
        if (ov > zval || (ov == zval && oi < zidx)) { zval = ov; zidx = oi; }
      }
      if ((tid & 63) == 0) { redA[tid >> 6] = zval; redI[tid >> 6] = zidx; }
    }
    __syncthreads();
    if (tid == 0) {
      double bv = redA[0]; int bx = redI[0];
#pragma unroll
      for (int w = 1; w < 4; ++w) {
        if (redA[w] > bv || (redA[w] == bv && redI[w] < bx)) { bv = redA[w]; bx = redI[w]; }
      }
      s_idx = bx;
      msk[bx] = 1.0f;
      out[OFF_I + (size_t)t * B_ + b] = (float)bx;
    }
    __syncthreads();
    // ---- K) gather next x ----
    if (tid < E_) sx[tid] = emb[((size_t)s_idx * B_ + b) * E_ + tid];
    __syncthreads();
  }
}

extern "C" void kernel_launch(void* const* d_in, const int* in_sizes, int n_in,
                              void* d_out, int out_size, void* d_ws, size_t ws_size,
                              hipStream_t stream) {
  const float* dec = (const float*)d_in[0];
  const float* emb = (const float*)d_in[1];
  const float* hx  = (const float*)d_in[2];
  const float* cx  = (const float*)d_in[3];
  const float* ctx = (const float*)d_in[4];
  const float* Wi  = (const float*)d_in[5];
  const float* bi  = (const float*)d_in[6];
  const float* Wh  = (const float*)d_in[7];
  const float* bh  = (const float*)d_in[8];
  const float* gWq = (const float*)d_in[9];
  const float* gbq = (const float*)d_in[10];
  const float* gWr = (const float*)d_in[11];
  const float* gbr = (const float*)d_in[12];
  const float* gv  = (const float*)d_in[13];
  const float* pWq = (const float*)d_in[14];
  const float* pbq = (const float*)d_in[15];
  const float* pWr = (const float*)d_in[16];
  const float* pbr = (const float*)d_in[17];
  const float* pv  = (const float*)d_in[18];
  float* out = (float*)d_out;
  char* w = (char*)d_ws;

  const size_t n_e = (size_t)B_ * H_ * S_;     // 33,554,432

  if (ws_size >= n_e * 12) {
    // tier C: all f32 tables (Eg, Ep, Elt). 393 KB/block-step logical reads.
    // Ep f32 perturbs pl by ~2e-7 — expected flips ~0.05 (analysis in journal).
    float* Eg = (float*)w;
    float* Ep = (float*)(w + n_e * 4);
    float* El = (float*)(w + n_e * 8);
    precompute_e<float,float,float><<<dim3(B_), dim3(256), 0, stream>>>(
        ctx, gWr, gbr, pWr, pbr, Eg, Ep, El);
    decoder_main<float,float,float><<<dim3(B_), dim3(NT), 0, stream>>>(
        dec, emb, hx, cx, Wi, bi, Wh, bh, gWq, gbq, gv, pWq, pbq, pv, Eg, Ep, El, out);
  } else {
    diag_write<<<dim3(1), dim3(64), 0, stream>>>(out, 700000.0f + (float)(ws_size >> 20));
  }
}

// Round 13
// 31506.598 us; speedup vs baseline: 3.3558x; 1.1806x over previous
//
#include <hip/hip_runtime.h>
#include <stdint.h>
#include <math.h>

#define S_ 256
#define B_ 1024
#define E_ 128
#define H_ 128
#define G4_ 512
#define NT 512

static const size_t OFF_P = 0;
static const size_t OFF_I = (size_t)S_ * B_ * S_;              // 67108864
static const size_t OFF_H = OFF_I + (size_t)S_ * B_;           // 67371008
static const size_t OFF_C = OFF_H + (size_t)B_ * H_;           // 67502080

template<typename T> struct alignas(2 * sizeof(T)) V2 { T x, y; };

// ---------------- threefry2x32 core (matches jax threefry2x32_p) ----------------
__device__ __forceinline__ void tf2x32(uint32_t k0, uint32_t k1,
                                       uint32_t x0, uint32_t x1,
                                       uint32_t& o0, uint32_t& o1) {
  uint32_t ks2 = k0 ^ k1 ^ 0x1BD11BDAu;
#define RO_(v,r) (((v) << (r)) | ((v) >> (32-(r))))
#define RND_(r) { x0 += x1; x1 = RO_(x1,r); x1 ^= x0; }
  x0 += k0; x1 += k1;
  RND_(13) RND_(15) RND_(26) RND_(6)
  x0 += k1; x1 += ks2 + 1u;
  RND_(17) RND_(29) RND_(16) RND_(24)
  x0 += ks2; x1 += k0 + 2u;
  RND_(13) RND_(15) RND_(26) RND_(6)
  x0 += k0; x1 += k1 + 3u;
  RND_(17) RND_(29) RND_(16) RND_(24)
  x0 += k1; x1 += ks2 + 4u;
  RND_(13) RND_(15) RND_(26) RND_(6)
  x0 += ks2; x1 += k0 + 5u;
  o0 = x0; o1 = x1;
#undef RND_
#undef RO_
}

// ---------------- fast branch-free f64 exp (rel err ~1e-16) ----------------
__device__ __forceinline__ double fexp(double x) {
  double t = x * 1.4426950408889634074;
  double n = rint(t);
  double r = __builtin_fma(n, -6.93147180369123816490e-01, x);   // ln2_hi (32b)
  r = __builtin_fma(n, -1.90821492927058770002e-10, r);          // ln2_lo
  double p = 2.08767569878681e-09;                                // 1/12!
  p = __builtin_fma(p, r, 2.50521083854417e-08);
  p = __builtin_fma(p, r, 2.75573192239859e-07);
  p = __builtin_fma(p, r, 2.75573192239859e-06);
  p = __builtin_fma(p, r, 2.48015873015873e-05);
  p = __builtin_fma(p, r, 1.98412698412698e-04);
  p = __builtin_fma(p, r, 1.38888888888889e-03);
  p = __builtin_fma(p, r, 8.33333333333333e-03);
  p = __builtin_fma(p, r, 4.16666666666667e-02);
  p = __builtin_fma(p, r, 1.66666666666667e-01);
  p = __builtin_fma(p, r, 5.0e-01);
  p = __builtin_fma(p, r, 1.0);
  p = __builtin_fma(p, r, 1.0);
  int ni = (int)n;
  double s = __longlong_as_double(((long long)(ni + 1023)) << 52);
  double res = p * s;
  return (x < -708.0) ? 0.0 : res;
}

__device__ __forceinline__ double ftanh(double x) {
  double a = fmin(fabs(x), 20.0);
  double w = fexp(-2.0 * a);
  double r = (1.0 - w) / (1.0 + w);
  return copysign(r, x);
}

__device__ __forceinline__ double fsigmoid(double x) {
  return 1.0 / (1.0 + fexp(-x));
}

__global__ void diag_write(float* out, float code) {
  if (threadIdx.x == 0 && blockIdx.x == 0) out[OFF_I] = code;
}

// ---------------- precompute tables (r8 scheme, f32) ----------------
// e[b][g][s] = sum_h ctx[s][b][h]*W[h][g] + bias[g]  (f64)
// Eg[b][g][s] = exp(-2 e_g), Ep[b][g][s] = exp(-2 e_p), Elt[b][s][g] = e_g.
template<typename ETg, typename ETp, typename ETe>
__global__ __launch_bounds__(256) void precompute_e(
    const float* __restrict__ ctx,
    const float* __restrict__ gWr, const float* __restrict__ gbr,
    const float* __restrict__ pWr, const float* __restrict__ pbr,
    ETg* __restrict__ Eg, ETp* __restrict__ Ep, ETe* __restrict__ Elt) {
  __shared__ float cb[64][129];
  const int b = blockIdx.x;
  const int tid = threadIdx.x;
  const int sl = tid & 63;
  const int gq = tid >> 6;

  for (int s0 = 0; s0 < S_; s0 += 64) {
    __syncthreads();
    for (int i = tid; i < 64 * H_; i += 256) {
      int r = i >> 7, h = i & 127;
      cb[r][h] = ctx[((size_t)(s0 + r) * B_ + b) * H_ + h];
    }
    __syncthreads();
    const int s = s0 + sl;
    for (int g0 = 0; g0 < H_; g0 += 4) {
      int g = g0 + gq;
      double a = 0.0, a2 = 0.0;
#pragma unroll 8
      for (int h = 0; h < H_; ++h) {
        double c = (double)cb[sl][h];
        a  = fma(c, (double)gWr[h * H_ + g], a);
        a2 = fma(c, (double)pWr[h * H_ + g], a2);
      }
      double e1 = a + (double)gbr[g];
      double e2 = a2 + (double)pbr[g];
      size_t idx = ((size_t)b * H_ + g) * S_ + s;
      Eg[idx] = (ETg)fexp(-2.0 * e1);
      Ep[idx] = (ETp)fexp(-2.0 * e2);
      Elt[((size_t)b * S_ + s) * H_ + g] = (ETe)e1;
    }
  }
}

// ---------------- main persistent per-b decoder (f64 math, 512 thr) ----------------
// 512 thr x 1024 blocks = 4 blocks/CU x 8 waves = 32 waves/CU (100% occupancy).
// D/H: 4-way h-split (tid = hq*128 + colpair), pair-reciprocal (r10-verified math).
template<typename ETg, typename ETp, typename ETe>
__global__ __launch_bounds__(NT) void decoder_main(
    const float* __restrict__ dec, const float* __restrict__ emb,
    const float* __restrict__ hx0, const float* __restrict__ cx0,
    const float* __restrict__ Wi, const float* __restrict__ bi,
    const float* __restrict__ Wh, const float* __restrict__ bh,
    const float* __restrict__ gWq, const float* __restrict__ gbq,
    const float* __restrict__ gv,
    const float* __restrict__ pWq, const float* __restrict__ pbq,
    const float* __restrict__ pv,
    const ETg* __restrict__ Eg_g, const ETp* __restrict__ Ep_g,
    const ETe* __restrict__ Elt_g,
    float* __restrict__ out) {
  __shared__ double gates[G4_];
  __shared__ double red0[NT];
  __shared__ double red1[NT];
  __shared__ double eq[H_], eq2[H_], glv[H_];
  __shared__ double sh[H_], sc[H_];
  __shared__ float  sx[E_];
  __shared__ double gl[S_];
  __shared__ double wbuf[S_];
  __shared__ double plv[S_];
  __shared__ double pex[S_];
  __shared__ float  gvs[H_], pvs[H_];
  __shared__ float  msk[S_];
  __shared__ uint32_t kk0[S_], kk1[S_];
  __shared__ double redM[4];
  __shared__ double redA[4];
  __shared__ int    redI[4];
  __shared__ int s_idx;

  const int b = blockIdx.x;
  const int tid = threadIdx.x;

  // ---- init ----
  if (tid < H_) {
    sh[tid] = (double)hx0[b * H_ + tid];
    sc[tid] = (double)cx0[b * H_ + tid];
    gvs[tid] = gv[tid]; pvs[tid] = pv[tid];
  } else if (tid < 2 * H_) {
    sx[tid - 128] = dec[b * E_ + (tid - 128)];
  }
  if (tid < S_) {
    msk[tid] = 0.f;
    // partitionable split: keys[t] = threefry2x32((0,42), (0,t))
    uint32_t a0, a1;
    tf2x32(0u, 42u, 0u, (uint32_t)tid, a0, a1);
    kk0[tid] = a0; kk1[tid] = a1;
  }
  const double bi_c = (double)bi[tid];
  const double bh_c = (double)bh[tid];
  const double gbq_c = (tid < H_) ? (double)gbq[tid] : 0.0;
  const double pbq_c = (tid < H_) ? (double)pbq[tid] : 0.0;
  const ETg* Eg_b  = Eg_g  + (size_t)b * H_ * S_;
  const ETp* Ep_b  = Ep_g  + (size_t)b * H_ * S_;
  const ETe* Elt_b = Elt_g + (size_t)b * S_ * H_;
  // D/H decomposition: tid = hq*128 + sc2; thread covers s-pair (2*sc2, 2*sc2+1),
  // h-range [hq*32, hq*32+32). Partials combined as (q0+q1)+(q2+q3).
  const int sc2 = tid & 127;
  const int hq  = tid >> 7;       // 0..3
  __syncthreads();

  for (int t = 0; t < S_; ++t) {
    // ---- A) gates = x@Wi + bi + h@Wh + bh (f64, seq-k, 1 gate/thread) ----
    {
      double a = 0.0;
      const float* WiT = Wi + tid;
#pragma unroll 8
      for (int k = 0; k < E_; ++k) a = fma((double)sx[k], (double)WiT[(size_t)k * G4_], a);
      a += bi_c;
      const float* WhT = Wh + tid;
#pragma unroll 8
      for (int k = 0; k < H_; ++k) a = fma(sh[k], (double)WhT[(size_t)k * G4_], a);
      gates[tid] = a + bh_c;
    }
    __syncthreads();
    // ---- B) LSTM elementwise ----
    if (tid < H_) {
      double si = fsigmoid(gates[tid]);
      double sf = fsigmoid(gates[H_ + tid]);
      double tg = ftanh(gates[2 * H_ + tid]);
      double so = fsigmoid(gates[3 * H_ + tid]);
      double cn = sf * sc[tid] + si * tg;
      double hn = so * ftanh(cn);
      sc[tid] = cn; sh[tid] = hn;
      if (t == S_ - 1) {
        out[OFF_H + (size_t)b * H_ + tid] = (float)hn;
        out[OFF_C + (size_t)b * H_ + tid] = (float)cn;
      }
    }
    __syncthreads();
    // ---- C) qp = hy@gWq + gbq; eq = exp(-2 qp) ----
    if (tid < H_) {
      double a = 0.0;
      const float* wq = gWq + tid;
#pragma unroll 8
      for (int k = 0; k < H_; ++k) a = fma(sh[k], (double)wq[k * H_], a);
      eq[tid] = fexp(-2.0 * (a + gbq_c));
    }
    __syncthreads();
    // ---- D) g logits: W = eq[h]*Eg; 4-way h-split, V2 loads, pair-rcp ----
    {
      const V2<ETg>* egp = reinterpret_cast<const V2<ETg>*>(Eg_b)
                           + (size_t)hq * 32 * (S_ / 2);
      double a0 = 0.0, a1 = 0.0;
#pragma unroll 8
      for (int hh = 0; hh < 32; ++hh) {
        int h = hq * 32 + hh;
        V2<ETg> w2 = egp[hh * (S_ / 2) + sc2];
        double eqh = eq[h];
        double gvh = (double)gvs[h];
        double W0 = eqh * (double)w2.x;
        double W1 = eqh * (double)w2.y;
        double rd = 1.0 / ((1.0 + W0) * (1.0 + W1));
        a0 = fma(gvh, (1.0 - W0) * (1.0 + W1) * rd, a0);
        a1 = fma(gvh, (1.0 - W1) * (1.0 + W0) * rd, a1);
      }
      red0[tid] = a0; red1[tid] = a1;
    }
    __syncthreads();
    if (tid < 128) {
      int s0 = 2 * tid, s1 = s0 + 1;
      double v0 = (red0[tid] + red0[tid + 128]) + (red0[tid + 256] + red0[tid + 384]);
      double v1 = (red1[tid] + red1[tid + 128]) + (red1[tid + 256] + red1[tid + 384]);
      gl[s0] = (msk[s0] != 0.f) ? -INFINITY : v0;
      gl[s1] = (msk[s1] != 0.f) ? -INFINITY : v1;
    }
    __syncthreads();
    // ---- E) softmax(gl) -> wbuf ----
    if (tid < S_) {
      double v = gl[tid];
      for (int o = 32; o; o >>= 1) v = fmax(v, __shfl_xor(v, o));
      if ((tid & 63) == 0) redM[tid >> 6] = v;
    }
    __syncthreads();
    {
      double m = fmax(fmax(redM[0], redM[1]), fmax(redM[2], redM[3]));
      if (tid < S_) pex[tid] = fexp(gl[tid] - m);
    }
    __syncthreads();
    if (tid < S_) {
      double sv = pex[tid];
      for (int o = 32; o; o >>= 1) sv += __shfl_xor(sv, o);
      if ((tid & 63) == 0) redM[tid >> 6] = sv;
    }
    __syncthreads();
    {
      double ssum = (redM[0] + redM[1]) + (redM[2] + redM[3]);
      if (tid < S_) wbuf[tid] = pex[tid] / ssum;
    }
    __syncthreads();
    // ---- F) g_l[g] = sum_s e_g[g][s]*w[s]  (Elt[s][g] coalesced, r8 shape) ----
    if (tid < H_) {
      double a = 0.0;
#pragma unroll 8
      for (int s = 0; s < S_; ++s)
        a = fma((double)Elt_b[(size_t)s * H_ + tid], wbuf[s], a);
      glv[tid] = a;
    }
    __syncthreads();
    // ---- G) qp2 = g_l@pWq + pbq; eq2 = exp(-2 qp2) ----
    if (tid < H_) {
      double a = 0.0;
      const float* wq = pWq + tid;
#pragma unroll 8
      for (int k = 0; k < H_; ++k) a = fma(glv[k], (double)wq[k * H_], a);
      eq2[tid] = fexp(-2.0 * (a + pbq_c));
    }
    __syncthreads();
    // ---- H) p logits: same decomposition as D ----
    {
      const V2<ETp>* epp = reinterpret_cast<const V2<ETp>*>(Ep_b)
                           + (size_t)hq * 32 * (S_ / 2);
      double a0 = 0.0, a1 = 0.0;
#pragma unroll 8
      for (int hh = 0; hh < 32; ++hh) {
        int h = hq * 32 + hh;
        V2<ETp> w2 = epp[hh * (S_ / 2) + sc2];
        double eqh = eq2[h];
        double pvh = (double)pvs[h];
        double W0 = eqh * (double)w2.x;
        double W1 = eqh * (double)w2.y;
        double rd = 1.0 / ((1.0 + W0) * (1.0 + W1));
        a0 = fma(pvh, (1.0 - W0) * (1.0 + W1) * rd, a0);
        a1 = fma(pvh, (1.0 - W1) * (1.0 + W0) * rd, a1);
      }
      red0[tid] = a0; red1[tid] = a1;
    }
    __syncthreads();
    if (tid < 128) {
      int s0 = 2 * tid, s1 = s0 + 1;
      double u0 = (red0[tid] + red0[tid + 128]) + (red0[tid + 256] + red0[tid + 384]);
      double u1 = (red1[tid] + red1[tid + 128]) + (red1[tid + 256] + red1[tid + 384]);
      plv[s0] = (msk[s0] != 0.f) ? -INFINITY : (10.0 * ftanh(u0));
      plv[s1] = (msk[s1] != 0.f) ? -INFINITY : (10.0 * ftanh(u1));
    }
    __syncthreads();
    // ---- I) probs = softmax(plv) -> out (f32) ----
    if (tid < S_) {
      double v = plv[tid];
      for (int o = 32; o; o >>= 1) v = fmax(v, __shfl_xor(v, o));
      if ((tid & 63) == 0) redM[tid >> 6] = v;
    }
    __syncthreads();
    {
      double m2 = fmax(fmax(redM[0], redM[1]), fmax(redM[2], redM[3]));
      if (tid < S_) pex[tid] = fexp(plv[tid] - m2);
    }
    __syncthreads();
    if (tid < S_) {
      double sv = pex[tid];
      for (int o = 32; o; o >>= 1) sv += __shfl_xor(sv, o);
      if ((tid & 63) == 0) redM[tid >> 6] = sv;
    }
    __syncthreads();
    {
      double ssum2 = (redM[0] + redM[1]) + (redM[2] + redM[3]);
      if (tid < S_) out[OFF_P + ((size_t)t * B_ + b) * S_ + tid] = (float)(pex[tid] / ssum2);
    }
    // ---- J) gumbel + argmax (partitionable bits: o0^o1 of tf(key_t,(0,j))) ----
    if (tid < S_) {
      double zval; int zidx;
      uint32_t j = (uint32_t)(b * S_ + tid);
      uint32_t r0, r1;
      tf2x32(kk0[t], kk1[t], 0u, j, r0, r1);
      uint32_t bits = r0 ^ r1;
      float f = __uint_as_float((bits >> 9) | 0x3f800000u) - 1.0f;
      float u = fmaxf(f, 1.17549435082228751e-38f);
      double gmb = -log(-log((double)u));
      zval = gmb + plv[tid]; zidx = tid;
      for (int o = 32; o; o >>= 1) {
        double ov = __shfl_xor(zval, o);
        int    oi = __shfl_xor(zidx, o);
        if (ov > zval || (ov == zval && oi < zidx)) { zval = ov; zidx = oi; }
      }
      if ((tid & 63) == 0) { redA[tid >> 6] = zval; redI[tid >> 6] = zidx; }
    }
    __syncthreads();
    if (tid == 0) {
      double bv = redA[0]; int bx = redI[0];
#pragma unroll
      for (int w = 1; w < 4; ++w) {
        if (redA[w] > bv || (redA[w] == bv && redI[w] < bx)) { bv = redA[w]; bx = redI[w]; }
      }
      s_idx = bx;
      msk[bx] = 1.0f;
      out[OFF_I + (size_t)t * B_ + b] = (float)bx;
    }
    __syncthreads();
    // ---- K) gather next x ----
    if (tid < E_) sx[tid] = emb[((size_t)s_idx * B_ + b) * E_ + tid];
    __syncthreads();
  }
}

extern "C" void kernel_launch(void* const* d_in, const int* in_sizes, int n_in,
                              void* d_out, int out_size, void* d_ws, size_t ws_size,
                              hipStream_t stream) {
  const float* dec = (const float*)d_in[0];
  const float* emb = (const float*)d_in[1];
  const float* hx  = (const float*)d_in[2];
  const float* cx  = (const float*)d_in[3];
  const float* ctx = (const float*)d_in[4];
  const float* Wi  = (const float*)d_in[5];
  const float* bi  = (const float*)d_in[6];
  const float* Wh  = (const float*)d_in[7];
  const float* bh  = (const float*)d_in[8];
  const float* gWq = (const float*)d_in[9];
  const float* gbq = (const float*)d_in[10];
  const float* gWr = (const float*)d_in[11];
  const float* gbr = (const float*)d_in[12];
  const float* gv  = (const float*)d_in[13];
  const float* pWq = (const float*)d_in[14];
  const float* pbq = (const float*)d_in[15];
  const float* pWr = (const float*)d_in[16];
  const float* pbr = (const float*)d_in[17];
  const float* pv  = (const float*)d_in[18];
  float* out = (float*)d_out;
  char* w = (char*)d_ws;

  const size_t n_e = (size_t)B_ * H_ * S_;     // 33,554,432

  if (ws_size >= n_e * 12) {
    // tier C: all f32 tables (Eg, Ep, Elt) — r12-verified numerics.
    float* Eg = (float*)w;
    float* Ep = (float*)(w + n_e * 4);
    float* El = (float*)(w + n_e * 8);
    precompute_e<float,float,float><<<dim3(B_), dim3(256), 0, stream>>>(
        ctx, gWr, gbr, pWr, pbr, Eg, Ep, El);
    decoder_main<float,float,float><<<dim3(B_), dim3(NT), 0, stream>>>(
        dec, emb, hx, cx, Wi, bi, Wh, bh, gWq, gbq, gv, pWq, pbq, pv, Eg, Ep, El, out);
  } else {
    diag_write<<<dim3(1), dim3(64), 0, stream>>>(out, 700000.0f + (float)(ws_size >> 20));
  }
}

// Round 14
// 25691.840 us; speedup vs baseline: 4.1153x; 1.2263x over previous
//
#include <hip/hip_runtime.h>
#include <stdint.h>
#include <math.h>

#define S_ 256
#define B_ 1024
#define E_ 128
#define H_ 128
#define G4_ 512
#define NT 512

static const size_t OFF_P = 0;
static const size_t OFF_I = (size_t)S_ * B_ * S_;              // 67108864
static const size_t OFF_H = OFF_I + (size_t)S_ * B_;           // 67371008
static const size_t OFF_C = OFF_H + (size_t)B_ * H_;           // 67502080

template<typename T> struct alignas(2 * sizeof(T)) V2 { T x, y; };

// ---------------- threefry2x32 core (matches jax threefry2x32_p) ----------------
__device__ __forceinline__ void tf2x32(uint32_t k0, uint32_t k1,
                                       uint32_t x0, uint32_t x1,
                                       uint32_t& o0, uint32_t& o1) {
  uint32_t ks2 = k0 ^ k1 ^ 0x1BD11BDAu;
#define RO_(v,r) (((v) << (r)) | ((v) >> (32-(r))))
#define RND_(r) { x0 += x1; x1 = RO_(x1,r); x1 ^= x0; }
  x0 += k0; x1 += k1;
  RND_(13) RND_(15) RND_(26) RND_(6)
  x0 += k1; x1 += ks2 + 1u;
  RND_(17) RND_(29) RND_(16) RND_(24)
  x0 += ks2; x1 += k0 + 2u;
  RND_(13) RND_(15) RND_(26) RND_(6)
  x0 += k0; x1 += k1 + 3u;
  RND_(17) RND_(29) RND_(16) RND_(24)
  x0 += k1; x1 += ks2 + 4u;
  RND_(13) RND_(15) RND_(26) RND_(6)
  x0 += ks2; x1 += k0 + 5u;
  o0 = x0; o1 = x1;
#undef RND_
#undef RO_
}

// ---------------- fast branch-free f64 exp (rel err ~1e-16) ----------------
__device__ __forceinline__ double fexp(double x) {
  double t = x * 1.4426950408889634074;
  double n = rint(t);
  double r = __builtin_fma(n, -6.93147180369123816490e-01, x);   // ln2_hi (32b)
  r = __builtin_fma(n, -1.90821492927058770002e-10, r);          // ln2_lo
  double p = 2.08767569878681e-09;                                // 1/12!
  p = __builtin_fma(p, r, 2.50521083854417e-08);
  p = __builtin_fma(p, r, 2.75573192239859e-07);
  p = __builtin_fma(p, r, 2.75573192239859e-06);
  p = __builtin_fma(p, r, 2.48015873015873e-05);
  p = __builtin_fma(p, r, 1.98412698412698e-04);
  p = __builtin_fma(p, r, 1.38888888888889e-03);
  p = __builtin_fma(p, r, 8.33333333333333e-03);
  p = __builtin_fma(p, r, 4.16666666666667e-02);
  p = __builtin_fma(p, r, 1.66666666666667e-01);
  p = __builtin_fma(p, r, 5.0e-01);
  p = __builtin_fma(p, r, 1.0);
  p = __builtin_fma(p, r, 1.0);
  int ni = (int)n;
  double s = __longlong_as_double(((long long)(ni + 1023)) << 52);
  double res = p * s;
  return (x < -708.0) ? 0.0 : res;
}

__device__ __forceinline__ double ftanh(double x) {
  double a = fmin(fabs(x), 20.0);
  double w = fexp(-2.0 * a);
  double r = (1.0 - w) / (1.0 + w);
  return copysign(r, x);
}

__device__ __forceinline__ double fsigmoid(double x) {
  return 1.0 / (1.0 + fexp(-x));
}

__global__ void diag_write(float* out, float code) {
  if (threadIdx.x == 0 && blockIdx.x == 0) out[OFF_I] = code;
}

// ---------------- precompute tables (r8 scheme, f32) ----------------
// e[b][g][s] = sum_h ctx[s][b][h]*W[h][g] + bias[g]  (f64)
// Eg[b][g][s] = exp(-2 e_g), Ep[b][g][s] = exp(-2 e_p), Elt[b][s][g] = e_g.
template<typename ETg, typename ETp, typename ETe>
__global__ __launch_bounds__(256) void precompute_e(
    const float* __restrict__ ctx,
    const float* __restrict__ gWr, const float* __restrict__ gbr,
    const float* __restrict__ pWr, const float* __restrict__ pbr,
    ETg* __restrict__ Eg, ETp* __restrict__ Ep, ETe* __restrict__ Elt) {
  __shared__ float cb[64][129];
  const int b = blockIdx.x;
  const int tid = threadIdx.x;
  const int sl = tid & 63;
  const int gq = tid >> 6;

  for (int s0 = 0; s0 < S_; s0 += 64) {
    __syncthreads();
    for (int i = tid; i < 64 * H_; i += 256) {
      int r = i >> 7, h = i & 127;
      cb[r][h] = ctx[((size_t)(s0 + r) * B_ + b) * H_ + h];
    }
    __syncthreads();
    const int s = s0 + sl;
    for (int g0 = 0; g0 < H_; g0 += 4) {
      int g = g0 + gq;
      double a = 0.0, a2 = 0.0;
#pragma unroll 8
      for (int h = 0; h < H_; ++h) {
        double c = (double)cb[sl][h];
        a  = fma(c, (double)gWr[h * H_ + g], a);
        a2 = fma(c, (double)pWr[h * H_ + g], a2);
      }
      double e1 = a + (double)gbr[g];
      double e2 = a2 + (double)pbr[g];
      size_t idx = ((size_t)b * H_ + g) * S_ + s;
      Eg[idx] = (ETg)fexp(-2.0 * e1);
      Ep[idx] = (ETp)fexp(-2.0 * e2);
      Elt[((size_t)b * S_ + s) * H_ + g] = (ETe)e1;
    }
  }
}

// ---------------- main persistent per-b decoder (f64 math, 512 thr) ----------------
// r13 skeleton (proven). Changes: D/H 4-elem-group single-reciprocal (2-ulp-safe),
// F 4-way s-split (f64 reassociation only).
template<typename ETg, typename ETp, typename ETe>
__global__ __launch_bounds__(NT) void decoder_main(
    const float* __restrict__ dec, const float* __restrict__ emb,
    const float* __restrict__ hx0, const float* __restrict__ cx0,
    const float* __restrict__ Wi, const float* __restrict__ bi,
    const float* __restrict__ Wh, const float* __restrict__ bh,
    const float* __restrict__ gWq, const float* __restrict__ gbq,
    const float* __restrict__ gv,
    const float* __restrict__ pWq, const float* __restrict__ pbq,
    const float* __restrict__ pv,
    const ETg* __restrict__ Eg_g, const ETp* __restrict__ Ep_g,
    const ETe* __restrict__ Elt_g,
    float* __restrict__ out) {
  __shared__ double gates[G4_];
  __shared__ double red0[NT];
  __shared__ double red1[NT];
  __shared__ double eq[H_], eq2[H_], glv[H_];
  __shared__ double sh[H_], sc[H_];
  __shared__ float  sx[E_];
  __shared__ double gl[S_];
  __shared__ double wbuf[S_];
  __shared__ double plv[S_];
  __shared__ double pex[S_];
  __shared__ float  gvs[H_], pvs[H_];
  __shared__ float  msk[S_];
  __shared__ uint32_t kk0[S_], kk1[S_];
  __shared__ double redM[4];
  __shared__ double redA[4];
  __shared__ int    redI[4];
  __shared__ int s_idx;

  const int b = blockIdx.x;
  const int tid = threadIdx.x;

  // ---- init ----
  if (tid < H_) {
    sh[tid] = (double)hx0[b * H_ + tid];
    sc[tid] = (double)cx0[b * H_ + tid];
    gvs[tid] = gv[tid]; pvs[tid] = pv[tid];
  } else if (tid < 2 * H_) {
    sx[tid - 128] = dec[b * E_ + (tid - 128)];
  }
  if (tid < S_) {
    msk[tid] = 0.f;
    // partitionable split: keys[t] = threefry2x32((0,42), (0,t))
    uint32_t a0, a1;
    tf2x32(0u, 42u, 0u, (uint32_t)tid, a0, a1);
    kk0[tid] = a0; kk1[tid] = a1;
  }
  const double bi_c = (double)bi[tid];
  const double bh_c = (double)bh[tid];
  const double gbq_c = (tid < H_) ? (double)gbq[tid] : 0.0;
  const double pbq_c = (tid < H_) ? (double)pbq[tid] : 0.0;
  const ETg* Eg_b  = Eg_g  + (size_t)b * H_ * S_;
  const ETp* Ep_b  = Ep_g  + (size_t)b * H_ * S_;
  const ETe* Elt_b = Elt_g + (size_t)b * S_ * H_;
  // D/H decomposition: tid = hq*128 + sc2; thread covers s-pair (2*sc2, 2*sc2+1),
  // h-range [hq*32, hq*32+32). Partials combined as (q0+q1)+(q2+q3).
  const int sc2 = tid & 127;
  const int hq  = tid >> 7;       // 0..3
  __syncthreads();

  for (int t = 0; t < S_; ++t) {
    // ---- A) gates = x@Wi + bi + h@Wh + bh (f64, seq-k, 1 gate/thread) ----
    {
      double a = 0.0;
      const float* WiT = Wi + tid;
#pragma unroll 8
      for (int k = 0; k < E_; ++k) a = fma((double)sx[k], (double)WiT[(size_t)k * G4_], a);
      a += bi_c;
      const float* WhT = Wh + tid;
#pragma unroll 8
      for (int k = 0; k < H_; ++k) a = fma(sh[k], (double)WhT[(size_t)k * G4_], a);
      gates[tid] = a + bh_c;
    }
    __syncthreads();
    // ---- B) LSTM elementwise ----
    if (tid < H_) {
      double si = fsigmoid(gates[tid]);
      double sf = fsigmoid(gates[H_ + tid]);
      double tg = ftanh(gates[2 * H_ + tid]);
      double so = fsigmoid(gates[3 * H_ + tid]);
      double cn = sf * sc[tid] + si * tg;
      double hn = so * ftanh(cn);
      sc[tid] = cn; sh[tid] = hn;
      if (t == S_ - 1) {
        out[OFF_H + (size_t)b * H_ + tid] = (float)hn;
        out[OFF_C + (size_t)b * H_ + tid] = (float)cn;
      }
    }
    __syncthreads();
    // ---- C) qp = hy@gWq + gbq; eq = exp(-2 qp) ----
    if (tid < H_) {
      double a = 0.0;
      const float* wq = gWq + tid;
#pragma unroll 8
      for (int k = 0; k < H_; ++k) a = fma(sh[k], (double)wq[k * H_], a);
      eq[tid] = fexp(-2.0 * (a + gbq_c));
    }
    __syncthreads();
    // ---- D) g logits: 4-way h-split, 2 h/iter, ONE f64 div per 4 tanh ----
    {
      const V2<ETg>* egp = reinterpret_cast<const V2<ETg>*>(Eg_b)
                           + (size_t)hq * 32 * (S_ / 2);
      double a0 = 0.0, a1 = 0.0;
#pragma unroll 4
      for (int hh = 0; hh < 32; hh += 2) {
        int h = hq * 32 + hh;
        V2<ETg> wa = egp[hh * (S_ / 2) + sc2];
        V2<ETg> wb = egp[(hh + 1) * (S_ / 2) + sc2];
        double eh0 = eq[h], eh1 = eq[h + 1];
        double W0 = eh0 * (double)wa.x;   // (h,   s0)
        double W1 = eh0 * (double)wa.y;   // (h,   s1)
        double W2 = eh1 * (double)wb.x;   // (h+1, s0)
        double W3 = eh1 * (double)wb.y;   // (h+1, s1)
        double p0 = 1.0 + W0, p1 = 1.0 + W1, p2 = 1.0 + W2, p3 = 1.0 + W3;
        double P02 = p0 * p2, P13 = p1 * p3;
        double rd = 1.0 / (P02 * P13);
        double q13 = P13 * rd;            // = 1/P02
        double q02 = P02 * rd;            // = 1/P13
        double gv0 = (double)gvs[h], gv1 = (double)gvs[h + 1];
        a0 = fma(gv0, (1.0 - W0) * p2 * q13, a0);
        a0 = fma(gv1, (1.0 - W2) * p0 * q13, a0);
        a1 = fma(gv0, (1.0 - W1) * p3 * q02, a1);
        a1 = fma(gv1, (1.0 - W3) * p1 * q02, a1);
      }
      red0[tid] = a0; red1[tid] = a1;
    }
    __syncthreads();
    if (tid < 128) {
      int s0 = 2 * tid, s1 = s0 + 1;
      double v0 = (red0[tid] + red0[tid + 128]) + (red0[tid + 256] + red0[tid + 384]);
      double v1 = (red1[tid] + red1[tid + 128]) + (red1[tid + 256] + red1[tid + 384]);
      gl[s0] = (msk[s0] != 0.f) ? -INFINITY : v0;
      gl[s1] = (msk[s1] != 0.f) ? -INFINITY : v1;
    }
    __syncthreads();
    // ---- E) softmax(gl) -> wbuf ----
    if (tid < S_) {
      double v = gl[tid];
      for (int o = 32; o; o >>= 1) v = fmax(v, __shfl_xor(v, o));
      if ((tid & 63) == 0) redM[tid >> 6] = v;
    }
    __syncthreads();
    {
      double m = fmax(fmax(redM[0], redM[1]), fmax(redM[2], redM[3]));
      if (tid < S_) pex[tid] = fexp(gl[tid] - m);
    }
    __syncthreads();
    if (tid < S_) {
      double sv = pex[tid];
      for (int o = 32; o; o >>= 1) sv += __shfl_xor(sv, o);
      if ((tid & 63) == 0) redM[tid >> 6] = sv;
    }
    __syncthreads();
    {
      double ssum = (redM[0] + redM[1]) + (redM[2] + redM[3]);
      if (tid < S_) wbuf[tid] = pex[tid] / ssum;
    }
    __syncthreads();
    // ---- F) g_l[g] = sum_s e_g[g][s]*w[s]; 4-way s-split, all 512 threads ----
    {
      int g = tid & 127, sq = tid >> 7;
      const ETe* col = Elt_b + (size_t)(sq * 64) * H_ + g;
      const double* wp = wbuf + sq * 64;
      double a = 0.0;
#pragma unroll 8
      for (int s = 0; s < 64; ++s)
        a = fma((double)col[(size_t)s * H_], wp[s], a);
      red0[tid] = a;
    }
    __syncthreads();
    if (tid < H_) glv[tid] = (red0[tid] + red0[tid + 128]) + (red0[tid + 256] + red0[tid + 384]);
    __syncthreads();
    // ---- G) qp2 = g_l@pWq + pbq; eq2 = exp(-2 qp2) ----
    if (tid < H_) {
      double a = 0.0;
      const float* wq = pWq + tid;
#pragma unroll 8
      for (int k = 0; k < H_; ++k) a = fma(glv[k], (double)wq[k * H_], a);
      eq2[tid] = fexp(-2.0 * (a + pbq_c));
    }
    __syncthreads();
    // ---- H) p logits: same 4-group decomposition as D ----
    {
      const V2<ETp>* epp = reinterpret_cast<const V2<ETp>*>(Ep_b)
                           + (size_t)hq * 32 * (S_ / 2);
      double a0 = 0.0, a1 = 0.0;
#pragma unroll 4
      for (int hh = 0; hh < 32; hh += 2) {
        int h = hq * 32 + hh;
        V2<ETp> wa = epp[hh * (S_ / 2) + sc2];
        V2<ETp> wb = epp[(hh + 1) * (S_ / 2) + sc2];
        double eh0 = eq2[h], eh1 = eq2[h + 1];
        double W0 = eh0 * (double)wa.x;
        double W1 = eh0 * (double)wa.y;
        double W2 = eh1 * (double)wb.x;
        double W3 = eh1 * (double)wb.y;
        double p0 = 1.0 + W0, p1 = 1.0 + W1, p2 = 1.0 + W2, p3 = 1.0 + W3;
        double P02 = p0 * p2, P13 = p1 * p3;
        double rd = 1.0 / (P02 * P13);
        double q13 = P13 * rd;
        double q02 = P02 * rd;
        double pv0 = (double)pvs[h], pv1 = (double)pvs[h + 1];
        a0 = fma(pv0, (1.0 - W0) * p2 * q13, a0);
        a0 = fma(pv1, (1.0 - W2) * p0 * q13, a0);
        a1 = fma(pv0, (1.0 - W1) * p3 * q02, a1);
        a1 = fma(pv1, (1.0 - W3) * p1 * q02, a1);
      }
      red0[tid] = a0; red1[tid] = a1;
    }
    __syncthreads();
    if (tid < 128) {
      int s0 = 2 * tid, s1 = s0 + 1;
      double u0 = (red0[tid] + red0[tid + 128]) + (red0[tid + 256] + red0[tid + 384]);
      double u1 = (red1[tid] + red1[tid + 128]) + (red1[tid + 256] + red1[tid + 384]);
      plv[s0] = (msk[s0] != 0.f) ? -INFINITY : (10.0 * ftanh(u0));
      plv[s1] = (msk[s1] != 0.f) ? -INFINITY : (10.0 * ftanh(u1));
    }
    __syncthreads();
    // ---- I) probs = softmax(plv) -> out (f32) ----
    if (tid < S_) {
      double v = plv[tid];
      for (int o = 32; o; o >>= 1) v = fmax(v, __shfl_xor(v, o));
      if ((tid & 63) == 0) redM[tid >> 6] = v;
    }
    __syncthreads();
    {
      double m2 = fmax(fmax(redM[0], redM[1]), fmax(redM[2], redM[3]));
      if (tid < S_) pex[tid] = fexp(plv[tid] - m2);
    }
    __syncthreads();
    if (tid < S_) {
      double sv = pex[tid];
      for (int o = 32; o; o >>= 1) sv += __shfl_xor(sv, o);
      if ((tid & 63) == 0) redM[tid >> 6] = sv;
    }
    __syncthreads();
    {
      double ssum2 = (redM[0] + redM[1]) + (redM[2] + redM[3]);
      if (tid < S_) out[OFF_P + ((size_t)t * B_ + b) * S_ + tid] = (float)(pex[tid] / ssum2);
    }
    // ---- J) gumbel + argmax (partitionable bits: o0^o1 of tf(key_t,(0,j))) ----
    if (tid < S_) {
      double zval; int zidx;
      uint32_t j = (uint32_t)(b * S_ + tid);
      uint32_t r0, r1;
      tf2x32(kk0[t], kk1[t], 0u, j, r0, r1);
      uint32_t bits = r0 ^ r1;
      float f = __uint_as_float((bits >> 9) | 0x3f800000u) - 1.0f;
      float u = fmaxf(f, 1.17549435082228751e-38f);
      double gmb = -log(-log((double)u));
      zval = gmb + plv[tid]; zidx = tid;
      for (int o = 32; o; o >>= 1) {
        double ov = __shfl_xor(zval, o);
        int    oi = __shfl_xor(zidx, o);
        if (ov > zval || (ov == zval && oi < zidx)) { zval = ov; zidx = oi; }
      }
      if ((tid & 63) == 0) { redA[tid >> 6] = zval; redI[tid >> 6] = zidx; }
    }
    __syncthreads();
    if (tid == 0) {
      double bv = redA[0]; int bx = redI[0];
#pragma unroll
      for (int w = 1; w < 4; ++w) {
        if (redA[w] > bv || (redA[w] == bv && redI[w] < bx)) { bv = redA[w]; bx = redI[w]; }
      }
      s_idx = bx;
      msk[bx] = 1.0f;
      out[OFF_I + (size_t)t * B_ + b] = (float)bx;
    }
    __syncthreads();
    // ---- K) gather next x ----
    if (tid < E_) sx[tid] = emb[((size_t)s_idx * B_ + b) * E_ + tid];
    __syncthreads();
  }
}

extern "C" void kernel_launch(void* const* d_in, const int* in_sizes, int n_in,
                              void* d_out, int out_size, void* d_ws, size_t ws_size,
                              hipStream_t stream) {
  const float* dec = (const float*)d_in[0];
  const float* emb = (const float*)d_in[1];
  const float* hx  = (const float*)d_in[2];
  const float* cx  = (const float*)d_in[3];
  const float* ctx = (const float*)d_in[4];
  const float* Wi  = (const float*)d_in[5];
  const float* bi  = (const float*)d_in[6];
  const float* Wh  = (const float*)d_in[7];
  const float* bh  = (const float*)d_in[8];
  const float* gWq = (const float*)d_in[9];
  const float* gbq = (const float*)d_in[10];
  const float* gWr = (const float*)d_in[11];
  const float* gbr = (const float*)d_in[12];
  const float* gv  = (const float*)d_in[13];
  const float* pWq = (const float*)d_in[14];
  const float* pbq = (const float*)d_in[15];
  const float* pWr = (const float*)d_in[16];
  const float* pbr = (const float*)d_in[17];
  const float* pv  = (const float*)d_in[18];
  float* out = (float*)d_out;
  char* w = (char*)d_ws;

  const size_t n_e = (size_t)B_ * H_ * S_;     // 33,554,432

  if (ws_size >= n_e * 12) {
    // tier C: all f32 tables (Eg, Ep, Elt) — r12/r13-verified numerics.
    float* Eg = (float*)w;
    float* Ep = (float*)(w + n_e * 4);
    float* El = (float*)(w + n_e * 8);
    precompute_e<float,float,float><<<dim3(B_), dim3(256), 0, stream>>>(
        ctx, gWr, gbr, pWr, pbr, Eg, Ep, El);
    decoder_main<float,float,float><<<dim3(B_), dim3(NT), 0, stream>>>(
        dec, emb, hx, cx, Wi, bi, Wh, bh, gWq, gbq, gv, pWq, pbq, pv, Eg, Ep, El, out);
  } else {
    diag_write<<<dim3(1), dim3(64), 0, stream>>>(out, 700000.0f + (float)(ws_size >> 20));
  }
}